// Round 1
// baseline (2773.622 us; speedup 1.0000x reference)
//
#include <hip/hip_runtime.h>
#include <cstddef>
#include <cstdint>

#define NN  100000
#define CC  512
#define FF  64
#define HH  128
#define EE  1600000
#define ESN 1000000

__device__ __forceinline__ unsigned short f2bf(float x){
  unsigned u = __builtin_bit_cast(unsigned, x);
  unsigned r = u + 0x7fffu + ((u >> 16) & 1u);
  return (unsigned short)(r >> 16);
}

// ---------------- init: zero accumulators ----------------
__global__ void k_init(float* cs, float* SE, float* U, int* cnt){
  int i = blockIdx.x*256 + threadIdx.x;
  if (i < CC) cs[i] = 0.f;
  if (i < CC*HH) SE[i] = 0.f;
  if (i < CC*FF) U[i] = 0.f;
  if (i < NN) cnt[i] = 0;
}

// ---------------- column sums of S ----------------
__global__ void k_colsum(const float* __restrict__ S, float* __restrict__ cs){
  int t = threadIdx.x;            // 128 threads, 4 cols each
  int c = t * 4;
  float ax=0.f, ay=0.f, az=0.f, aw=0.f;
  for (int r = blockIdx.x; r < NN; r += gridDim.x){
    float4 v = *(const float4*)(S + (size_t)r*CC + c);
    ax += v.x; ay += v.y; az += v.z; aw += v.w;
  }
  atomicAdd(&cs[c+0], ax); atomicAdd(&cs[c+1], ay);
  atomicAdd(&cs[c+2], az); atomicAdd(&cs[c+3], aw);
}

__global__ void k_w(const float* __restrict__ cs, float* __restrict__ w){
  int c = blockIdx.x*256 + threadIdx.x;
  if (c < CC){
    float d = cs[c] - 1.f;
    if (d < 0.f) d = 0.f;
    w[c] = 1.f / (d + 1.f);
  }
}

// ---------------- raw_feat build (fp32) ----------------
__global__ void k_rf(const int* __restrict__ lanef, const int* __restrict__ typef,
                     const int* __restrict__ lenf, const int* __restrict__ nodef,
                     const float* __restrict__ WL, const float* __restrict__ WT,
                     const float* __restrict__ WLen, const float* __restrict__ WNode,
                     float* __restrict__ rf){
  int gid = blockIdx.x*256 + threadIdx.x;
  int n = gid >> 5, q = gid & 31;
  if (n >= NN) return;
  int col = (q & 7) * 4;
  const float* src;
  int sel = q >> 3;
  if (sel == 0)      src = WL   + (size_t)lanef[n]*32 + col;
  else if (sel == 1) src = WT   + (size_t)typef[n]*32 + col;
  else if (sel == 2) src = WLen + (size_t)lenf[n]*32 + col;
  else               src = WNode+ (size_t)nodef[n]*32 + col;
  *(float4*)(rf + (size_t)n*HH + q*4) = *(const float4*)src;
}

// ---------------- edge counting sort ----------------
__global__ void k_hist(const int* __restrict__ adj, int* __restrict__ cnt){
  int e = blockIdx.x*256 + threadIdx.x;
  if (e < EE) atomicAdd(&cnt[adj[e]], 1);
}
__global__ void k_scan_a(const int* __restrict__ cnt, int* __restrict__ loc, int* __restrict__ bsum){
  __shared__ int sh[256];
  int b = blockIdx.x, t = threadIdx.x;
  int i = b*256 + t;
  int v = (i < NN) ? cnt[i] : 0;
  sh[t] = v; __syncthreads();
  for (int off = 1; off < 256; off <<= 1){
    int x = (t >= off) ? sh[t-off] : 0;
    __syncthreads();
    sh[t] += x;
    __syncthreads();
  }
  if (i < NN) loc[i] = sh[t] - v;
  if (t == 255) bsum[b] = sh[t];
}
__global__ void k_scan_b(const int* __restrict__ bsum, int* __restrict__ boff, int nb){
  __shared__ int sh[512];
  int t = threadIdx.x;
  int v = (t < nb) ? bsum[t] : 0;
  sh[t] = v; __syncthreads();
  for (int off = 1; off < 512; off <<= 1){
    int x = (t >= off) ? sh[t-off] : 0;
    __syncthreads();
    sh[t] += x;
    __syncthreads();
  }
  if (t < nb) boff[t] = sh[t] - v;
}
__global__ void k_scan_c(int* __restrict__ rowstart, const int* __restrict__ boff, int* __restrict__ cursor){
  int i = blockIdx.x*256 + threadIdx.x;
  if (i < NN){
    int v = rowstart[i] + boff[i >> 8];
    rowstart[i] = v; cursor[i] = v;
  }
  if (i == NN) rowstart[NN] = EE;
}
__global__ void k_scatter(const int* __restrict__ adj, int* __restrict__ cursor, int* __restrict__ sdst){
  int e = blockIdx.x*256 + threadIdx.x;
  if (e < EE){
    int s = adj[e], d = adj[EE + e];
    int pos = atomicAdd(&cursor[s], 1);
    sdst[pos] = d;
  }
}

// ---------------- OUT[C,F] += S[N,C]^T @ V[N,F] (split-K, atomics) ----------------
template<int F>
__global__ __launch_bounds__(256) void k_gemmT(const float* __restrict__ S,
                                               const float* __restrict__ V,
                                               float* __restrict__ OUT){
  constexpr int HJ = F/32;
  __shared__ float S_lds[8][256];
  __shared__ float V_lds[8][F];
  const int t = threadIdx.x;
  const int tx = t & 7;          // h-group
  const int ty = t >> 3;         // c-group [0,32)
  const int c0 = blockIdx.x * 256;
  const int rows_per = (NN + gridDim.y - 1) / gridDim.y;
  const int r0 = blockIdx.y * rows_per;
  const int r1 = min(r0 + rows_per, NN);
  float acc[8][HJ][4];
  #pragma unroll
  for (int i=0;i<8;i++)
    #pragma unroll
    for (int j=0;j<HJ;j++)
      #pragma unroll
      for (int k2=0;k2<4;k2++) acc[i][j][k2] = 0.f;

  for (int rb = r0; rb < r1; rb += 8){
    __syncthreads();
    for (int i = t; i < 8*64; i += 256){
      int r = i >> 6, q = i & 63;
      int n = rb + r;
      float4 v = {0.f,0.f,0.f,0.f};
      if (n < r1) v = *(const float4*)(S + (size_t)n*CC + c0 + q*4);
      *(float4*)&S_lds[r][q*4] = v;
    }
    constexpr int VQ = F/4;
    for (int i = t; i < 8*VQ; i += 256){
      int r = i / VQ, q = i - r*VQ;
      int n = rb + r;
      float4 v = {0.f,0.f,0.f,0.f};
      if (n < r1) v = *(const float4*)(V + (size_t)n*F + q*4);
      *(float4*)&V_lds[r][q*4] = v;
    }
    __syncthreads();
    #pragma unroll 1
    for (int r = 0; r < 8; ++r){
      float sv[8];
      *(float4*)&sv[0] = *(float4*)&S_lds[r][ty*8];
      *(float4*)&sv[4] = *(float4*)&S_lds[r][ty*8 + 4];
      float vv[HJ][4];
      #pragma unroll
      for (int jq=0;jq<HJ;jq++)
        *(float4*)&vv[jq][0] = *(float4*)&V_lds[r][jq*32 + tx*4];
      #pragma unroll
      for (int ic=0;ic<8;ic++)
        #pragma unroll
        for (int jq=0;jq<HJ;jq++)
          #pragma unroll
          for (int jj=0;jj<4;jj++)
            acc[ic][jq][jj] += sv[ic] * vv[jq][jj];
    }
  }
  for (int ic=0;ic<8;ic++){
    int cc2 = c0 + ty*8 + ic;
    for (int jq=0;jq<HJ;jq++)
      for (int jj=0;jj<4;jj++)
        atomicAdd(&OUT[(size_t)cc2*F + jq*32 + tx*4 + jj], acc[ic][jq][jj]);
  }
}

// ---- struct_emb = w*SE ; Q = w * (struct_emb @ gcn_W) ----
__global__ void k_sepq(const float* __restrict__ SE, const float* __restrict__ w,
                       const float* __restrict__ gcn, float* __restrict__ sem,
                       float* __restrict__ Q){
  __shared__ float row[HH];
  int c = blockIdx.x, f = threadIdx.x; // 64 threads
  float wc = w[c];
  for (int h = f; h < HH; h += 64){
    float v = wc * SE[c*HH + h];
    row[h] = v;
    sem[c*HH + h] = v;
  }
  __syncthreads();
  float p = 0.f;
  for (int h = 0; h < HH; ++h) p += row[h] * gcn[h*FF + f];
  Q[c*FF + f] = wc * p;
}

// ---------------- OUT[N,F] (=|+=) SRC[N,K] @ B[K,F] (+bias) ----------------
// B staged in LDS as bf16, XOR-swizzled rows (16B granules) for conflict-free b128 reads.
template<int F, int FH, int K, bool ACC, bool BIAS>
__global__ __launch_bounds__(512) void k_gemmN(const float* __restrict__ SRC,
                                               const float* __restrict__ B,
                                               const float* __restrict__ bias,
                                               float* __restrict__ OUT){
  __shared__ unsigned short Bt[FH*K];
  const int t = threadIdx.x;
  const int fbase = blockIdx.y * FH;
  for (int i = t; i < K*FH; i += 512){
    int c = i / FH;
    int fl = i - c*FH;
    float v = B[(size_t)c*F + fbase + fl];
    Bt[fl*K + (((c >> 3) ^ (fl & 7)) << 3) + (c & 7)] = f2bf(v);
  }
  __syncthreads();
  const int lane = t & 63;
  const int wid  = t >> 6;
  const bool act = lane < FH;
  float bv = 0.f;
  if (BIAS && act) bv = bias[fbase + lane];
  const int swzbase = act ? (lane*K) : 0;
  const int sm = (lane & 7) << 3;

  for (int n0 = (blockIdx.x*8 + wid)*4; n0 < NN; n0 += gridDim.x*8*4){
    float a0=0.f, a1=0.f, a2=0.f, a3=0.f;
    for (int c0 = 0; c0 < K; c0 += 8){
      float4 v0a = *(const float4*)(SRC + (size_t)(n0+0)*K + c0);
      float4 v0b = *(const float4*)(SRC + (size_t)(n0+0)*K + c0 + 4);
      float4 v1a = *(const float4*)(SRC + (size_t)(n0+1)*K + c0);
      float4 v1b = *(const float4*)(SRC + (size_t)(n0+1)*K + c0 + 4);
      float4 v2a = *(const float4*)(SRC + (size_t)(n0+2)*K + c0);
      float4 v2b = *(const float4*)(SRC + (size_t)(n0+2)*K + c0 + 4);
      float4 v3a = *(const float4*)(SRC + (size_t)(n0+3)*K + c0);
      float4 v3b = *(const float4*)(SRC + (size_t)(n0+3)*K + c0 + 4);
      if (act){
        uint4 u = *(const uint4*)&Bt[swzbase + (c0 ^ sm)];
        float m0 = __builtin_bit_cast(float, u.x << 16);
        float m1 = __builtin_bit_cast(float, u.x & 0xffff0000u);
        float m2 = __builtin_bit_cast(float, u.y << 16);
        float m3 = __builtin_bit_cast(float, u.y & 0xffff0000u);
        float m4 = __builtin_bit_cast(float, u.z << 16);
        float m5 = __builtin_bit_cast(float, u.z & 0xffff0000u);
        float m6 = __builtin_bit_cast(float, u.w << 16);
        float m7 = __builtin_bit_cast(float, u.w & 0xffff0000u);
        a0 += v0a.x*m0 + v0a.y*m1 + v0a.z*m2 + v0a.w*m3 + v0b.x*m4 + v0b.y*m5 + v0b.z*m6 + v0b.w*m7;
        a1 += v1a.x*m0 + v1a.y*m1 + v1a.z*m2 + v1a.w*m3 + v1b.x*m4 + v1b.y*m5 + v1b.z*m6 + v1b.w*m7;
        a2 += v2a.x*m0 + v2a.y*m1 + v2a.z*m2 + v2a.w*m3 + v2b.x*m4 + v2b.y*m5 + v2b.z*m6 + v2b.w*m7;
        a3 += v3a.x*m0 + v3a.y*m1 + v3a.z*m2 + v3a.w*m3 + v3b.x*m4 + v3b.y*m5 + v3b.z*m6 + v3b.w*m7;
      }
    }
    if (act){
      size_t o = (size_t)n0*F + fbase + lane;
      if (ACC){
        OUT[o      ] += a0 + bv;
        OUT[o +   F] += a1 + bv;
        OUT[o + 2*F] += a2 + bv;
        OUT[o + 3*F] += a3 + bv;
      } else {
        OUT[o      ] = a0 + bv;
        OUT[o +   F] = a1 + bv;
        OUT[o + 2*F] = a2 + bv;
        OUT[o + 3*F] = a3 + bv;
      }
    }
  }
}

// ---------------- T[s,:] = sum over edges (src=s) of R[dst,:] ----------------
__global__ void k_esum(const int* __restrict__ rowstart, const int* __restrict__ sdst,
                       const float* __restrict__ R, float* __restrict__ T){
  int wg = (blockIdx.x*256 + threadIdx.x) >> 6;
  int lane = threadIdx.x & 63;
  if (wg >= NN) return;
  int e0 = rowstart[wg], e1 = rowstart[wg+1];
  float acc = 0.f;
  for (int e = e0; e < e1; ++e){
    int d = sdst[e];
    acc += R[(size_t)d*FF + lane];
  }
  T[(size_t)wg*FF + lane] = acc;
}

// ---------------- softmax over C (axis 0) of w*U ----------------
__global__ void k_softmax(const float* __restrict__ U, const float* __restrict__ w,
                          float* __restrict__ fa){
  __shared__ float red[CC];
  int f = blockIdx.x, t = threadIdx.x; // 512 threads
  float v = w[t] * U[t*FF + f];
  red[t] = v; __syncthreads();
  for (int s = 256; s > 0; s >>= 1){
    if (t < s) red[t] = fmaxf(red[t], red[t+s]);
    __syncthreads();
  }
  float mx = red[0]; __syncthreads();
  float e = expf(v - mx);
  red[t] = e; __syncthreads();
  for (int s = 256; s > 0; s >>= 1){
    if (t < s) red[t] += red[t+s];
    __syncthreads();
  }
  float sum = red[0];
  fa[t*FF + f] = e / sum;
}

// ---------------- small GEMMs ----------------
__global__ void k_fe(const float* __restrict__ fa, const float* __restrict__ sem,
                     float* __restrict__ FE){
  int g = blockIdx.x, h = threadIdx.x; // 128
  float a = 0.f;
  for (int c = 0; c < CC; ++c) a += fa[c*FF + g] * sem[c*HH + h];
  FE[g*HH + h] = a;
}
__global__ void k_fw(const float* __restrict__ FE, const float* __restrict__ linW,
                     float* __restrict__ FW){
  int g = blockIdx.x, f = threadIdx.x; // 128, guard 100
  if (f >= 100) return;
  float a = 0.f;
  for (int h = 0; h < HH; ++h) a += FE[g*HH + h] * linW[(256 + h)*100 + f];
  FW[g*100 + f] = a;
}
__global__ void k_m(const float* __restrict__ sem, const float* __restrict__ fa,
                    const float* __restrict__ FW, const float* __restrict__ linW,
                    const float* __restrict__ w, float* __restrict__ M){
  int c = blockIdx.x, f = threadIdx.x; // 128, guard 100
  if (f >= 100) return;
  float a = 0.f;
  for (int h = 0; h < HH; ++h) a += sem[c*HH + h] * linW[(128 + h)*100 + f];
  for (int g = 0; g < FF; ++g) a += fa[c*FF + g] * FW[g*100 + f];
  M[c*100 + f] = w[c] * a;
}

// ---------------- edge scoring: pred[e] = X[a].X[b] ----------------
__global__ __launch_bounds__(256) void k_edot(const int* __restrict__ sedge,
                                              const float* __restrict__ X,
                                              float* __restrict__ out){
  int hw = (blockIdx.x*256 + threadIdx.x) >> 5;
  int hl = threadIdx.x & 31;
  if (hw >= ESN) return;
  int a = sedge[hw];
  int b = sedge[ESN + hw];
  float p = 0.f;
  if (hl < 25){
    float4 xa = *(const float4*)(X + (size_t)a*100 + hl*4);
    float4 xb = *(const float4*)(X + (size_t)b*100 + hl*4);
    p = xa.x*xb.x + xa.y*xb.y + xa.z*xb.z + xa.w*xb.w;
  }
  #pragma unroll
  for (int off = 16; off > 0; off >>= 1)
    p += __shfl_down(p, off, 32);
  if (hl == 0) out[hw] = p;
}

extern "C" void kernel_launch(void* const* d_in, const int* in_sizes, int n_in,
                              void* d_out, int out_size, void* d_ws, size_t ws_size,
                              hipStream_t stream){
  (void)in_sizes; (void)n_in; (void)out_size; (void)ws_size;
  const int*   lanef = (const int*)  d_in[0];
  const int*   typef = (const int*)  d_in[1];
  const int*   lenf  = (const int*)  d_in[2];
  const int*   nodef = (const int*)  d_in[3];
  const int*   adj   = (const int*)  d_in[4];
  const float* S     = (const float*)d_in[6];
  const int*   sedge = (const int*)  d_in[7];
  const float* WL    = (const float*)d_in[8];
  const float* WT    = (const float*)d_in[9];
  const float* WLen  = (const float*)d_in[10];
  const float* WNode = (const float*)d_in[11];
  const float* gcn   = (const float*)d_in[12];
  const float* linW  = (const float*)d_in[13];
  const float* linB  = (const float*)d_in[14];
  float* out = (float*)d_out;

  char* p = (char*)d_ws;
  auto alloc = [&](size_t bytes) -> void* {
    void* r = (void*)p;
    p += (bytes + 255) & ~(size_t)255;
    return r;
  };
  float* cs  = (float*)alloc(CC*4);
  float* w   = (float*)alloc(CC*4);
  float* SE  = (float*)alloc(CC*HH*4);
  float* sem = (float*)alloc(CC*HH*4);
  float* Q   = (float*)alloc(CC*FF*4);
  float* U   = (float*)alloc(CC*FF*4);
  float* fa  = (float*)alloc(CC*FF*4);
  float* FE  = (float*)alloc(FF*HH*4);
  float* FW  = (float*)alloc(FF*100*4);
  float* M   = (float*)alloc(CC*100*4);
  int* cnt      = (int*)alloc((size_t)NN*4);
  int* rowstart = (int*)alloc((size_t)(NN+1)*4);
  int* cursor   = (int*)alloc((size_t)NN*4);
  int* bsum     = (int*)alloc(512*4);
  int* boff     = (int*)alloc(512*4);
  int* sdst     = (int*)alloc((size_t)EE*4);
  float* rf = (float*)alloc((size_t)NN*HH*4);
  float* R  = (float*)alloc((size_t)NN*FF*4);
  float* T  = (float*)alloc((size_t)NN*FF*4);
  float* X  = (float*)alloc((size_t)NN*100*4);

  const int NB = (NN + 255) / 256;   // 391

  k_init<<<NB, 256, 0, stream>>>(cs, SE, U, cnt);
  k_colsum<<<512, 128, 0, stream>>>(S, cs);
  k_w<<<2, 256, 0, stream>>>(cs, w);
  k_rf<<<(NN*32)/256, 256, 0, stream>>>(lanef, typef, lenf, nodef, WL, WT, WLen, WNode, rf);

  k_hist<<<(EE+255)/256, 256, 0, stream>>>(adj, cnt);
  k_scan_a<<<NB, 256, 0, stream>>>(cnt, rowstart, bsum);
  k_scan_b<<<1, 512, 0, stream>>>(bsum, boff, NB);
  k_scan_c<<<NB, 256, 0, stream>>>(rowstart, boff, cursor);
  k_scatter<<<(EE+255)/256, 256, 0, stream>>>(adj, cursor, sdst);

  k_gemmT<128><<<dim3(2,128), 256, 0, stream>>>(S, rf, SE);
  k_sepq<<<CC, 64, 0, stream>>>(SE, w, gcn, sem, Q);
  k_gemmN<64,64,512,false,false><<<dim3(512,1), 512, 0, stream>>>(S, Q, nullptr, R);
  k_esum<<<(NN*64)/256, 256, 0, stream>>>(rowstart, sdst, R, T);
  k_gemmT<64><<<dim3(2,128), 256, 0, stream>>>(S, T, U);
  k_softmax<<<FF, 512, 0, stream>>>(U, w, fa);
  k_fe<<<FF, 128, 0, stream>>>(fa, sem, FE);
  k_fw<<<FF, 128, 0, stream>>>(FE, linW, FW);
  k_m<<<CC, 128, 0, stream>>>(sem, fa, FW, linW, w, M);

  k_gemmN<100,50,512,false,true><<<dim3(256,2), 512, 0, stream>>>(S, M, linB, X);
  k_gemmN<100,50,128,true,false><<<dim3(256,2), 512, 0, stream>>>(rf, linW, nullptr, X);

  k_edot<<<(ESN*32)/256, 256, 0, stream>>>(sedge, X, out);
}

// Round 2
// 1658.525 us; speedup vs baseline: 1.6723x; 1.6723x over previous
//
#include <hip/hip_runtime.h>
#include <cstddef>
#include <cstdint>

#define NN  100000
#define CC  512
#define FF  64
#define HH  128
#define EE  1600000
#define ESN 1000000
#define XST 112   // padded X row stride (100 -> 112), pad cols are exactly 0

typedef __attribute__((ext_vector_type(8))) short s16x8;
typedef __attribute__((ext_vector_type(4))) float f32x4;

__device__ __forceinline__ unsigned short f2bf(float x){
  unsigned u = __builtin_bit_cast(unsigned, x);
  unsigned r = u + 0x7fffu + ((u >> 16) & 1u);
  return (unsigned short)(r >> 16);
}
__device__ __forceinline__ float bf2f(unsigned short h){
  return __builtin_bit_cast(float, (unsigned)h << 16);
}

// ---------------- init: zero accumulators ----------------
__global__ void k_init(float* cs, float* SE, float* U, int* cnt){
  int i = blockIdx.x*256 + threadIdx.x;
  if (i < CC) cs[i] = 0.f;
  if (i < CC*HH) SE[i] = 0.f;
  if (i < CC*FF) U[i] = 0.f;
  if (i < NN) cnt[i] = 0;
}

// ---------------- column sums of S + cast S -> bf16 ----------------
__global__ void k_prep(const float* __restrict__ S, float* __restrict__ cs,
                       unsigned short* __restrict__ S_bf){
  int t = threadIdx.x;            // 128 threads, 4 cols each
  int c = t * 4;
  float ax=0.f, ay=0.f, az=0.f, aw=0.f;
  for (int r = blockIdx.x; r < NN; r += gridDim.x){
    float4 v = *(const float4*)(S + (size_t)r*CC + c);
    ax += v.x; ay += v.y; az += v.z; aw += v.w;
    ushort4 b;
    b.x = f2bf(v.x); b.y = f2bf(v.y); b.z = f2bf(v.z); b.w = f2bf(v.w);
    *(ushort4*)(S_bf + (size_t)r*CC + c) = b;
  }
  atomicAdd(&cs[c+0], ax); atomicAdd(&cs[c+1], ay);
  atomicAdd(&cs[c+2], az); atomicAdd(&cs[c+3], aw);
}

__global__ void k_w(const float* __restrict__ cs, float* __restrict__ w){
  int c = blockIdx.x*256 + threadIdx.x;
  if (c < CC){
    float d = cs[c] - 1.f;
    if (d < 0.f) d = 0.f;
    w[c] = 1.f / (d + 1.f);
  }
}

// ---------------- raw_feat build -> rf2 = [hi(128) | lo(128)] bf16 ----------------
__global__ void k_rf(const int* __restrict__ lanef, const int* __restrict__ typef,
                     const int* __restrict__ lenf, const int* __restrict__ nodef,
                     const float* __restrict__ WL, const float* __restrict__ WT,
                     const float* __restrict__ WLen, const float* __restrict__ WNode,
                     unsigned short* __restrict__ rf2){
  int gid = blockIdx.x*256 + threadIdx.x;
  int n = gid >> 5, q = gid & 31;
  if (n >= NN) return;
  int col = (q & 7) * 4;
  const float* src;
  int sel = q >> 3;
  if (sel == 0)      src = WL   + (size_t)lanef[n]*32 + col;
  else if (sel == 1) src = WT   + (size_t)typef[n]*32 + col;
  else if (sel == 2) src = WLen + (size_t)lenf[n]*32 + col;
  else               src = WNode+ (size_t)nodef[n]*32 + col;
  float4 v = *(const float4*)src;
  ushort4 h, lo;
  h.x = f2bf(v.x); lo.x = f2bf(v.x - bf2f(h.x));
  h.y = f2bf(v.y); lo.y = f2bf(v.y - bf2f(h.y));
  h.z = f2bf(v.z); lo.z = f2bf(v.z - bf2f(h.z));
  h.w = f2bf(v.w); lo.w = f2bf(v.w - bf2f(h.w));
  *(ushort4*)(rf2 + (size_t)n*256 + q*4) = h;
  *(ushort4*)(rf2 + (size_t)n*256 + 128 + q*4) = lo;
}

// ---------------- edge counting sort ----------------
__global__ void k_hist(const int* __restrict__ adj, int* __restrict__ cnt){
  int e = blockIdx.x*256 + threadIdx.x;
  if (e < EE) atomicAdd(&cnt[adj[e]], 1);
}
__global__ void k_scan_a(const int* __restrict__ cnt, int* __restrict__ loc, int* __restrict__ bsum){
  __shared__ int sh[256];
  int b = blockIdx.x, t = threadIdx.x;
  int i = b*256 + t;
  int v = (i < NN) ? cnt[i] : 0;
  sh[t] = v; __syncthreads();
  for (int off = 1; off < 256; off <<= 1){
    int x = (t >= off) ? sh[t-off] : 0;
    __syncthreads();
    sh[t] += x;
    __syncthreads();
  }
  if (i < NN) loc[i] = sh[t] - v;
  if (t == 255) bsum[b] = sh[t];
}
__global__ void k_scan_b(const int* __restrict__ bsum, int* __restrict__ boff, int nb){
  __shared__ int sh[512];
  int t = threadIdx.x;
  int v = (t < nb) ? bsum[t] : 0;
  sh[t] = v; __syncthreads();
  for (int off = 1; off < 512; off <<= 1){
    int x = (t >= off) ? sh[t-off] : 0;
    __syncthreads();
    sh[t] += x;
    __syncthreads();
  }
  if (t < nb) boff[t] = sh[t] - v;
}
__global__ void k_scan_c(int* __restrict__ rowstart, const int* __restrict__ boff, int* __restrict__ cursor){
  int i = blockIdx.x*256 + threadIdx.x;
  if (i < NN){
    int v = rowstart[i] + boff[i >> 8];
    rowstart[i] = v; cursor[i] = v;
  }
  if (i == NN) rowstart[NN] = EE;
}
__global__ void k_scatter(const int* __restrict__ adj, int* __restrict__ cursor, int* __restrict__ sdst){
  int e = blockIdx.x*256 + threadIdx.x;
  if (e < EE){
    int s = adj[e], d = adj[EE + e];
    int pos = atomicAdd(&cursor[s], 1);
    sdst[pos] = d;
  }
}

// ---------------- OUT[C,F] += S[N,C]^T @ V[N,F] (split-K, atomics) ----------------
// V2 mode: V is rf2 bf16 hi/lo pairs [N,256], reconstructed to fp32.
template<int F, bool V2>
__global__ __launch_bounds__(256) void k_gemmT(const float* __restrict__ S,
                                               const float* __restrict__ V,
                                               const unsigned short* __restrict__ V2p,
                                               float* __restrict__ OUT){
  constexpr int HJ = F/32;
  __shared__ float S_lds[8][256];
  __shared__ float V_lds[8][F];
  const int t = threadIdx.x;
  const int tx = t & 7;          // h-group
  const int ty = t >> 3;         // c-group [0,32)
  const int c0 = blockIdx.x * 256;
  const int rows_per = (NN + gridDim.y - 1) / gridDim.y;
  const int r0 = blockIdx.y * rows_per;
  const int r1 = min(r0 + rows_per, NN);
  float acc[8][HJ][4];
  #pragma unroll
  for (int i=0;i<8;i++)
    #pragma unroll
    for (int j=0;j<HJ;j++)
      #pragma unroll
      for (int k2=0;k2<4;k2++) acc[i][j][k2] = 0.f;

  for (int rb = r0; rb < r1; rb += 8){
    __syncthreads();
    for (int i = t; i < 8*64; i += 256){
      int r = i >> 6, q = i & 63;
      int n = rb + r;
      float4 v = {0.f,0.f,0.f,0.f};
      if (n < r1) v = *(const float4*)(S + (size_t)n*CC + c0 + q*4);
      *(float4*)&S_lds[r][q*4] = v;
    }
    constexpr int VQ = F/4;
    for (int i = t; i < 8*VQ; i += 256){
      int r = i / VQ, q = i - r*VQ;
      int n = rb + r;
      float4 v = {0.f,0.f,0.f,0.f};
      if (n < r1){
        if (V2){
          ushort4 h  = *(const ushort4*)(V2p + (size_t)n*256 + q*4);
          ushort4 lo = *(const ushort4*)(V2p + (size_t)n*256 + 128 + q*4);
          v.x = bf2f(h.x) + bf2f(lo.x);
          v.y = bf2f(h.y) + bf2f(lo.y);
          v.z = bf2f(h.z) + bf2f(lo.z);
          v.w = bf2f(h.w) + bf2f(lo.w);
        } else {
          v = *(const float4*)(V + (size_t)n*F + q*4);
        }
      }
      *(float4*)&V_lds[r][q*4] = v;
    }
    __syncthreads();
    #pragma unroll 1
    for (int r = 0; r < 8; ++r){
      float sv[8];
      *(float4*)&sv[0] = *(float4*)&S_lds[r][ty*8];
      *(float4*)&sv[4] = *(float4*)&S_lds[r][ty*8 + 4];
      float vv[HJ][4];
      #pragma unroll
      for (int jq=0;jq<HJ;jq++)
        *(float4*)&vv[jq][0] = *(float4*)&V_lds[r][jq*32 + tx*4];
      #pragma unroll
      for (int ic=0;ic<8;ic++)
        #pragma unroll
        for (int jq=0;jq<HJ;jq++)
          #pragma unroll
          for (int jj=0;jj<4;jj++)
            acc[ic][jq][jj] += sv[ic] * vv[jq][jj];
    }
  }
  for (int ic=0;ic<8;ic++){
    int cc2 = c0 + ty*8 + ic;
    for (int jq=0;jq<HJ;jq++)
      for (int jj=0;jj<4;jj++)
        atomicAdd(&OUT[(size_t)cc2*F + jq*32 + tx*4 + jj], acc[ic][jq][jj]);
  }
}

// ---- struct_emb = w*SE ; Q = w * (struct_emb @ gcn_W) ----
__global__ void k_sepq(const float* __restrict__ SE, const float* __restrict__ w,
                       const float* __restrict__ gcn, float* __restrict__ sem,
                       float* __restrict__ Q){
  __shared__ float row[HH];
  int c = blockIdx.x, f = threadIdx.x; // 64 threads
  float wc = w[c];
  for (int h = f; h < HH; h += 64){
    float v = wc * SE[c*HH + h];
    row[h] = v;
    sem[c*HH + h] = v;
  }
  __syncthreads();
  float p = 0.f;
  for (int h = 0; h < HH; ++h) p += row[h] * gcn[h*FF + f];
  Q[c*FF + f] = wc * p;
}

// ---------------- MFMA GEMM: OUT[N, FT*16] (=|+=) A_bf16[N,K] @ B[K,F] ----------------
// A: row-major bf16, loaded directly from global (lane groups cover full 64B lines).
// B: staged whole in LDS, k-major per column, 16B XOR swizzle -> ~2-way max conflicts.
// FSRC = valid cols of Bsrc (also its row stride); cols >= FSRC are zero pad.
// KSRCM: source row = k & KSRCM (lets K=256 map onto the 128-row W1 twice for hi/lo).
template<int FT, int K, int FSRC, int KSRCM, bool ACCUM, bool BIAS>
__global__ __launch_bounds__(1024) void k_mgemm(const unsigned short* __restrict__ A,
                                                const float* __restrict__ Bsrc,
                                                const float* __restrict__ bias,
                                                float* __restrict__ OUT, int ost){
  __shared__ unsigned short Bt[FT*16*K];
  const int t = threadIdx.x;
  for (int i = t; i < FT*16*K; i += 1024){
    int f = i / K, k = i - f*K;
    float v = (f < FSRC) ? Bsrc[(size_t)(k & KSRCM)*FSRC + f] : 0.f;
    Bt[f*K + ((((k >> 3) ^ (f & 7)) << 3) | (k & 7))] = f2bf(v);
  }
  __syncthreads();
  const int lane = t & 63;
  const int wid  = t >> 6;           // 0..15
  const int cb   = lane & 15;        // A-row low / D-col low
  const int q    = lane >> 4;        // 0..3
  const int s    = cb & 7;
  const int arow = min(blockIdx.x*256 + wid*16 + cb, NN-1);
  const unsigned short* ap = A + (size_t)arow*K + q*8;

  f32x4 acc[FT];
  #pragma unroll
  for (int ft = 0; ft < FT; ++ft) acc[ft] = (f32x4){0.f,0.f,0.f,0.f};

  #pragma unroll 2
  for (int kt = 0; kt < K/32; ++kt){
    s16x8 a = *(const s16x8*)(ap + kt*32);
    int boff = (((kt*4 + q) ^ s) << 3);
    #pragma unroll
    for (int ft = 0; ft < FT; ++ft){
      s16x8 b = *(const s16x8*)&Bt[(ft*16 + cb)*K + boff];
      acc[ft] = __builtin_amdgcn_mfma_f32_16x16x32_bf16(a, b, acc[ft], 0, 0, 0);
    }
  }

  const int nb = blockIdx.x*256 + wid*16 + q*4;
  #pragma unroll
  for (int ft = 0; ft < FT; ++ft){
    int f = ft*16 + cb;
    float bv = 0.f;
    if (BIAS) bv = (f < FSRC) ? bias[f] : 0.f;
    #pragma unroll
    for (int r = 0; r < 4; ++r){
      int n = nb + r;
      if (n < NN){
        size_t o = (size_t)n*ost + f;
        if (ACCUM) OUT[o] += acc[ft][r];
        else       OUT[o] = acc[ft][r] + bv;
      }
    }
  }
}

// ---------------- T[s,:] = sum over edges (src=s) of R[dst,:] ----------------
__global__ void k_esum(const int* __restrict__ rowstart, const int* __restrict__ sdst,
                       const float* __restrict__ R, float* __restrict__ T){
  int wg = (blockIdx.x*256 + threadIdx.x) >> 6;
  int lane = threadIdx.x & 63;
  if (wg >= NN) return;
  int e0 = rowstart[wg], e1 = rowstart[wg+1];
  float acc = 0.f;
  for (int e = e0; e < e1; ++e){
    int d = sdst[e];
    acc += R[(size_t)d*FF + lane];
  }
  T[(size_t)wg*FF + lane] = acc;
}

// ---------------- softmax over C (axis 0) of w*U ----------------
__global__ void k_softmax(const float* __restrict__ U, const float* __restrict__ w,
                          float* __restrict__ fa){
  __shared__ float red[CC];
  int f = blockIdx.x, t = threadIdx.x; // 512 threads
  float v = w[t] * U[t*FF + f];
  red[t] = v; __syncthreads();
  for (int sft = 256; sft > 0; sft >>= 1){
    if (t < sft) red[t] = fmaxf(red[t], red[t+sft]);
    __syncthreads();
  }
  float mx = red[0]; __syncthreads();
  float e = expf(v - mx);
  red[t] = e; __syncthreads();
  for (int sft = 256; sft > 0; sft >>= 1){
    if (t < sft) red[t] += red[t+sft];
    __syncthreads();
  }
  float sum = red[0];
  fa[t*FF + f] = e / sum;
}

// ---------------- small GEMMs ----------------
__global__ void k_fe(const float* __restrict__ fa, const float* __restrict__ sem,
                     float* __restrict__ FE){
  int g = blockIdx.x, h = threadIdx.x; // 128
  float a = 0.f;
  for (int c = 0; c < CC; ++c) a += fa[c*FF + g] * sem[c*HH + h];
  FE[g*HH + h] = a;
}
__global__ void k_fw(const float* __restrict__ FE, const float* __restrict__ linW,
                     float* __restrict__ FW){
  int g = blockIdx.x, f = threadIdx.x; // 128, guard 100
  if (f >= 100) return;
  float a = 0.f;
  for (int h = 0; h < HH; ++h) a += FE[g*HH + h] * linW[(256 + h)*100 + f];
  FW[g*100 + f] = a;
}
__global__ void k_m(const float* __restrict__ sem, const float* __restrict__ fa,
                    const float* __restrict__ FW, const float* __restrict__ linW,
                    const float* __restrict__ w, float* __restrict__ M){
  int c = blockIdx.x, f = threadIdx.x; // 128, guard 100
  if (f >= 100) return;
  float a = 0.f;
  for (int h = 0; h < HH; ++h) a += sem[c*HH + h] * linW[(128 + h)*100 + f];
  for (int g = 0; g < FF; ++g) a += fa[c*FF + g] * FW[g*100 + f];
  M[c*100 + f] = w[c] * a;
}

// ---------------- edge scoring: pred[e] = X[a].X[b] (stride XST, pad cols = 0) ----------------
__global__ __launch_bounds__(256) void k_edot(const int* __restrict__ sedge,
                                              const float* __restrict__ X,
                                              float* __restrict__ out){
  int hw = (blockIdx.x*256 + threadIdx.x) >> 5;
  int hl = threadIdx.x & 31;
  if (hw >= ESN) return;
  int a = sedge[hw];
  int b = sedge[ESN + hw];
  float p = 0.f;
  if (hl < 28){
    float4 xa = *(const float4*)(X + (size_t)a*XST + hl*4);
    float4 xb = *(const float4*)(X + (size_t)b*XST + hl*4);
    p = xa.x*xb.x + xa.y*xb.y + xa.z*xb.z + xa.w*xb.w;
  }
  #pragma unroll
  for (int off = 16; off > 0; off >>= 1)
    p += __shfl_down(p, off, 32);
  if (hl == 0) out[hw] = p;
}

extern "C" void kernel_launch(void* const* d_in, const int* in_sizes, int n_in,
                              void* d_out, int out_size, void* d_ws, size_t ws_size,
                              hipStream_t stream){
  (void)in_sizes; (void)n_in; (void)out_size; (void)ws_size;
  const int*   lanef = (const int*)  d_in[0];
  const int*   typef = (const int*)  d_in[1];
  const int*   lenf  = (const int*)  d_in[2];
  const int*   nodef = (const int*)  d_in[3];
  const int*   adj   = (const int*)  d_in[4];
  const float* S     = (const float*)d_in[6];
  const int*   sedge = (const int*)  d_in[7];
  const float* WL    = (const float*)d_in[8];
  const float* WT    = (const float*)d_in[9];
  const float* WLen  = (const float*)d_in[10];
  const float* WNode = (const float*)d_in[11];
  const float* gcn   = (const float*)d_in[12];
  const float* linW  = (const float*)d_in[13];
  const float* linB  = (const float*)d_in[14];
  float* out = (float*)d_out;

  char* p = (char*)d_ws;
  auto alloc = [&](size_t bytes) -> void* {
    void* r = (void*)p;
    p += (bytes + 255) & ~(size_t)255;
    return r;
  };
  float* cs  = (float*)alloc(CC*4);
  float* w   = (float*)alloc(CC*4);
  float* SE  = (float*)alloc(CC*HH*4);
  float* sem = (float*)alloc(CC*HH*4);
  float* Q   = (float*)alloc(CC*FF*4);
  float* U   = (float*)alloc(CC*FF*4);
  float* fa  = (float*)alloc(CC*FF*4);
  float* FE  = (float*)alloc(FF*HH*4);
  float* FW  = (float*)alloc(FF*100*4);
  float* M   = (float*)alloc(CC*100*4);
  int* cnt      = (int*)alloc((size_t)NN*4);
  int* rowstart = (int*)alloc((size_t)(NN+1)*4);
  int* cursor   = (int*)alloc((size_t)NN*4);
  int* bsum     = (int*)alloc(512*4);
  int* boff     = (int*)alloc(512*4);
  int* sdst     = (int*)alloc((size_t)EE*4);
  unsigned short* S_bf = (unsigned short*)alloc((size_t)NN*CC*2);   // 102.4 MB
  unsigned short* rf2  = (unsigned short*)alloc((size_t)NN*256*2);  // 51.2 MB
  float* R  = (float*)alloc((size_t)NN*FF*4);                       // 25.6 MB
  float* T  = (float*)alloc((size_t)NN*FF*4);                       // 25.6 MB
  // X [NN,112] fp32 = 44.8 MB aliases [R;T] (51.2 MB): R,T are dead before X1 writes.
  float* X  = R;

  const int NB = (NN + 255) / 256;   // 391

  k_init<<<NB, 256, 0, stream>>>(cs, SE, U, cnt);
  k_prep<<<512, 128, 0, stream>>>(S, cs, S_bf);
  k_w<<<2, 256, 0, stream>>>(cs, w);
  k_rf<<<(NN*32)/256, 256, 0, stream>>>(lanef, typef, lenf, nodef, WL, WT, WLen, WNode, rf2);

  k_hist<<<(EE+255)/256, 256, 0, stream>>>(adj, cnt);
  k_scan_a<<<NB, 256, 0, stream>>>(cnt, rowstart, bsum);
  k_scan_b<<<1, 512, 0, stream>>>(bsum, boff, NB);
  k_scan_c<<<NB, 256, 0, stream>>>(rowstart, boff, cursor);
  k_scatter<<<(EE+255)/256, 256, 0, stream>>>(adj, cursor, sdst);

  k_gemmT<128,true><<<dim3(2,128), 256, 0, stream>>>(S, nullptr, rf2, SE);
  k_sepq<<<CC, 64, 0, stream>>>(SE, w, gcn, sem, Q);
  k_mgemm<4,512,64,511,false,false><<<NB, 1024, 0, stream>>>(S_bf, Q, nullptr, R, FF);
  k_esum<<<(NN*64)/256, 256, 0, stream>>>(rowstart, sdst, R, T);
  k_gemmT<64,false><<<dim3(2,128), 256, 0, stream>>>(S, T, nullptr, U);
  k_softmax<<<FF, 512, 0, stream>>>(U, w, fa);
  k_fe<<<FF, 128, 0, stream>>>(fa, sem, FE);
  k_fw<<<FF, 128, 0, stream>>>(FE, linW, FW);
  k_m<<<CC, 128, 0, stream>>>(sem, fa, FW, linW, w, M);

  // X = S@M + bias  (K=512), then X += [rf_hi|rf_lo]@W1 (K=256, rows k&127)
  k_mgemm<7,512,100,511,false,true ><<<NB, 1024, 0, stream>>>(S_bf, M, linB, X, XST);
  k_mgemm<7,256,100,127,true ,false><<<NB, 1024, 0, stream>>>(rf2, linW, nullptr, X, XST);

  k_edot<<<(ESN*32)/256, 256, 0, stream>>>(sedge, X, out);
}

// Round 3
// 1062.861 us; speedup vs baseline: 2.6096x; 1.5604x over previous
//
#include <hip/hip_runtime.h>
#include <cstddef>
#include <cstdint>

#define NN  100000
#define CC  512
#define FF  64
#define HH  128
#define EE  1600000
#define ESN 1000000
#define XST 112      // padded X row stride (100 -> 112), pad cols are exactly 0
#define NSPLIT 125   // k-split blocks for k_tgemm
#define KPB 800      // k-rows per block (125*800 = 100000 exactly, 800%32==0)

typedef __attribute__((ext_vector_type(8))) short s16x8;
typedef __attribute__((ext_vector_type(4))) float f32x4;

__device__ __forceinline__ unsigned short f2bf(float x){
  unsigned u = __builtin_bit_cast(unsigned, x);
  unsigned r = u + 0x7fffu + ((u >> 16) & 1u);
  return (unsigned short)(r >> 16);
}
__device__ __forceinline__ float bf2f(unsigned short h){
  return __builtin_bit_cast(float, (unsigned)h << 16);
}

// ---------------- init: zero accumulators ----------------
__global__ void k_init(float* cs, int* cnt){
  int i = blockIdx.x*256 + threadIdx.x;
  if (i < CC) cs[i] = 0.f;
  if (i < NN) cnt[i] = 0;
}

// ---------------- column sums of S + cast S -> bf16 ----------------
__global__ void k_prep(const float* __restrict__ S, float* __restrict__ cs,
                       unsigned short* __restrict__ S_bf){
  int t = threadIdx.x;            // 128 threads, 4 cols each
  int c = t * 4;
  float ax=0.f, ay=0.f, az=0.f, aw=0.f;
  for (int r = blockIdx.x; r < NN; r += gridDim.x){
    float4 v = *(const float4*)(S + (size_t)r*CC + c);
    ax += v.x; ay += v.y; az += v.z; aw += v.w;
    ushort4 b;
    b.x = f2bf(v.x); b.y = f2bf(v.y); b.z = f2bf(v.z); b.w = f2bf(v.w);
    *(ushort4*)(S_bf + (size_t)r*CC + c) = b;
  }
  atomicAdd(&cs[c+0], ax); atomicAdd(&cs[c+1], ay);
  atomicAdd(&cs[c+2], az); atomicAdd(&cs[c+3], aw);
}

__global__ void k_w(const float* __restrict__ cs, float* __restrict__ w){
  int c = blockIdx.x*256 + threadIdx.x;
  if (c < CC){
    float d = cs[c] - 1.f;
    if (d < 0.f) d = 0.f;
    w[c] = 1.f / (d + 1.f);
  }
}

// ---------------- raw_feat build -> rf2 = [hi(128) | lo(128)] bf16 ----------------
__global__ void k_rf(const int* __restrict__ lanef, const int* __restrict__ typef,
                     const int* __restrict__ lenf, const int* __restrict__ nodef,
                     const float* __restrict__ WL, const float* __restrict__ WT,
                     const float* __restrict__ WLen, const float* __restrict__ WNode,
                     unsigned short* __restrict__ rf2){
  int gid = blockIdx.x*256 + threadIdx.x;
  int n = gid >> 5, q = gid & 31;
  if (n >= NN) return;
  int col = (q & 7) * 4;
  const float* src;
  int sel = q >> 3;
  if (sel == 0)      src = WL   + (size_t)lanef[n]*32 + col;
  else if (sel == 1) src = WT   + (size_t)typef[n]*32 + col;
  else if (sel == 2) src = WLen + (size_t)lenf[n]*32 + col;
  else               src = WNode+ (size_t)nodef[n]*32 + col;
  float4 v = *(const float4*)src;
  ushort4 h, lo;
  h.x = f2bf(v.x); lo.x = f2bf(v.x - bf2f(h.x));
  h.y = f2bf(v.y); lo.y = f2bf(v.y - bf2f(h.y));
  h.z = f2bf(v.z); lo.z = f2bf(v.z - bf2f(h.z));
  h.w = f2bf(v.w); lo.w = f2bf(v.w - bf2f(h.w));
  *(ushort4*)(rf2 + (size_t)n*256 + q*4) = h;
  *(ushort4*)(rf2 + (size_t)n*256 + 128 + q*4) = lo;
}

// ---------------- edge counting sort ----------------
__global__ void k_hist(const int* __restrict__ adj, int* __restrict__ cnt){
  int e = blockIdx.x*256 + threadIdx.x;
  if (e < EE) atomicAdd(&cnt[adj[e]], 1);
}
__global__ void k_scan_a(const int* __restrict__ cnt, int* __restrict__ loc, int* __restrict__ bsum){
  __shared__ int sh[256];
  int b = blockIdx.x, t = threadIdx.x;
  int i = b*256 + t;
  int v = (i < NN) ? cnt[i] : 0;
  sh[t] = v; __syncthreads();
  for (int off = 1; off < 256; off <<= 1){
    int x = (t >= off) ? sh[t-off] : 0;
    __syncthreads();
    sh[t] += x;
    __syncthreads();
  }
  if (i < NN) loc[i] = sh[t] - v;
  if (t == 255) bsum[b] = sh[t];
}
__global__ void k_scan_b(const int* __restrict__ bsum, int* __restrict__ boff, int nb){
  __shared__ int sh[512];
  int t = threadIdx.x;
  int v = (t < nb) ? bsum[t] : 0;
  sh[t] = v; __syncthreads();
  for (int off = 1; off < 512; off <<= 1){
    int x = (t >= off) ? sh[t-off] : 0;
    __syncthreads();
    sh[t] += x;
    __syncthreads();
  }
  if (t < nb) boff[t] = sh[t] - v;
}
__global__ void k_scan_c(int* __restrict__ rowstart, const int* __restrict__ boff, int* __restrict__ cursor){
  int i = blockIdx.x*256 + threadIdx.x;
  if (i < NN){
    int v = rowstart[i] + boff[i >> 8];
    rowstart[i] = v; cursor[i] = v;
  }
  if (i == NN) rowstart[NN] = EE;
}
__global__ void k_scatter(const int* __restrict__ adj, int* __restrict__ cursor, int* __restrict__ sdst){
  int e = blockIdx.x*256 + threadIdx.x;
  if (e < EE){
    int s = adj[e], d = adj[EE + e];
    int pos = atomicAdd(&cursor[s], 1);
    sdst[pos] = d;
  }
}

// ------- MFMA split-k GEMM: P[b] = S[b-slice]^T @ V[b-slice]  ([512, F] partials) -------
// S_bf row-major [N,512] bf16; V row-major bf16 [N,VST] (first F cols used).
// LDS: transposed tiles, pitch 40 elems (80B): b128 frag reads 16B-aligned, ~2-way banks.
template<int F, int VST>
__global__ __launch_bounds__(1024) void k_tgemm(const unsigned short* __restrict__ Sb,
                                                const unsigned short* __restrict__ V,
                                                float* __restrict__ P){
  __shared__ unsigned short S_t[512*40];
  __shared__ unsigned short V_t[F*40];
  constexpr int HT = F/16;
  const int t = threadIdx.x;
  const int lane = t & 63, wid = t >> 6;   // 16 waves
  const int cb = lane & 15, q = lane >> 4;
  const int n0 = blockIdx.x * KPB;
  const int n1 = min(n0 + KPB, NN);
  const int scg = t >> 4;                  // 0..63 (c-octet)
  const int sp  = t & 15;                  // row-pair
  f32x4 acc[2][HT];
  #pragma unroll
  for (int a=0;a<2;a++)
    #pragma unroll
    for (int b=0;b<HT;b++) acc[a][b] = (f32x4){0.f,0.f,0.f,0.f};

  for (int rb = n0; rb < n1; rb += 32){
    __syncthreads();
    { // stage S_t[c][k] for k-rows rb..rb+31
      int na = rb + 2*sp, nb2 = na + 1;
      s16x8 va = (s16x8){0,0,0,0,0,0,0,0}, vb = va;
      if (na  < n1) va = *(const s16x8*)(Sb + (size_t)na *512 + scg*8);
      if (nb2 < n1) vb = *(const s16x8*)(Sb + (size_t)nb2*512 + scg*8);
      int k2 = 2*sp;
      #pragma unroll
      for (int m = 0; m < 8; ++m){
        unsigned pack = (unsigned)(unsigned short)va[m] | ((unsigned)(unsigned short)vb[m] << 16);
        *(unsigned*)&S_t[(scg*8 + m)*40 + k2] = pack;
      }
    }
    if (t < 2*F){ // stage V_t[h][k]
      int vcg = t >> 4;      // 0..F/8-1
      int vp  = t & 15;
      int na = rb + 2*vp, nb2 = na + 1;
      s16x8 va = (s16x8){0,0,0,0,0,0,0,0}, vb = va;
      if (na  < n1) va = *(const s16x8*)(V + (size_t)na *VST + vcg*8);
      if (nb2 < n1) vb = *(const s16x8*)(V + (size_t)nb2*VST + vcg*8);
      int k2 = 2*vp;
      #pragma unroll
      for (int m = 0; m < 8; ++m){
        unsigned pack = (unsigned)(unsigned short)va[m] | ((unsigned)(unsigned short)vb[m] << 16);
        *(unsigned*)&V_t[(vcg*8 + m)*40 + k2] = pack;
      }
    }
    __syncthreads();
    s16x8 af[2];
    #pragma unroll
    for (int ct = 0; ct < 2; ++ct){
      int c = wid*32 + ct*16 + cb;
      af[ct] = *(const s16x8*)&S_t[c*40 + q*8];
    }
    #pragma unroll
    for (int ht = 0; ht < HT; ++ht){
      s16x8 bf = *(const s16x8*)&V_t[(ht*16 + cb)*40 + q*8];
      #pragma unroll
      for (int ct = 0; ct < 2; ++ct)
        acc[ct][ht] = __builtin_amdgcn_mfma_f32_16x16x32_bf16(af[ct], bf, acc[ct][ht], 0, 0, 0);
    }
  }
  float* Pb = P + (size_t)blockIdx.x * 512 * F;
  #pragma unroll
  for (int ct = 0; ct < 2; ++ct)
    #pragma unroll
    for (int ht = 0; ht < HT; ++ht)
      #pragma unroll
      for (int r = 0; r < 4; ++r)
        Pb[(wid*32 + ct*16 + q*4 + r)*F + ht*16 + cb] = acc[ct][ht][r];
}

template<int F>
__global__ void k_reduce(const float* __restrict__ P, float* __restrict__ OUT){
  int i = blockIdx.x*256 + threadIdx.x;    // < 512*F
  float s = 0.f;
  for (int b = 0; b < NSPLIT; ++b) s += P[(size_t)b*(512*F) + i];
  OUT[i] = s;
}

// ---- struct_emb = w*SE ; Q = w * (struct_emb @ gcn_W) ----
__global__ void k_sepq(const float* __restrict__ SE, const float* __restrict__ w,
                       const float* __restrict__ gcn, float* __restrict__ sem,
                       float* __restrict__ Q){
  __shared__ float row[HH];
  int c = blockIdx.x, f = threadIdx.x; // 64 threads
  float wc = w[c];
  for (int h = f; h < HH; h += 64){
    float v = wc * SE[c*HH + h];
    row[h] = v;
    sem[c*HH + h] = v;
  }
  __syncthreads();
  float p = 0.f;
  for (int h = 0; h < HH; ++h) p += row[h] * gcn[h*FF + f];
  Q[c*FF + f] = wc * p;
}

// ---------------- MFMA GEMM: OUT[N, FT*16] (=|+=) A_bf16[N,K] @ B[K,F] ----------------
template<int FT, int K, int FSRC, int KSRCM, bool ACCUM, bool BIAS, bool OUTBF>
__global__ __launch_bounds__(1024) void k_mgemm(const unsigned short* __restrict__ A,
                                                const float* __restrict__ Bsrc,
                                                const float* __restrict__ bias,
                                                void* __restrict__ OUTv, int ost){
  __shared__ unsigned short Bt[FT*16*K];
  const int t = threadIdx.x;
  for (int i = t; i < FT*16*K; i += 1024){
    int f = i / K, k = i - f*K;
    float v = (f < FSRC) ? Bsrc[(size_t)(k & KSRCM)*FSRC + f] : 0.f;
    Bt[f*K + ((((k >> 3) ^ (f & 7)) << 3) | (k & 7))] = f2bf(v);
  }
  __syncthreads();
  const int lane = t & 63;
  const int wid  = t >> 6;           // 0..15
  const int cb   = lane & 15;
  const int q    = lane >> 4;
  const int s    = cb & 7;
  const int arow = min(blockIdx.x*256 + wid*16 + cb, NN-1);
  const unsigned short* ap = A + (size_t)arow*K + q*8;

  f32x4 acc[FT];
  #pragma unroll
  for (int ft = 0; ft < FT; ++ft) acc[ft] = (f32x4){0.f,0.f,0.f,0.f};

  #pragma unroll 2
  for (int kt = 0; kt < K/32; ++kt){
    s16x8 a = *(const s16x8*)(ap + kt*32);
    int boff = (((kt*4 + q) ^ s) << 3);
    #pragma unroll
    for (int ft = 0; ft < FT; ++ft){
      s16x8 b = *(const s16x8*)&Bt[(ft*16 + cb)*K + boff];
      acc[ft] = __builtin_amdgcn_mfma_f32_16x16x32_bf16(a, b, acc[ft], 0, 0, 0);
    }
  }

  const int nb = blockIdx.x*256 + wid*16 + q*4;
  #pragma unroll
  for (int ft = 0; ft < FT; ++ft){
    int f = ft*16 + cb;
    float bv = 0.f;
    if (BIAS) bv = (f < FSRC) ? bias[f] : 0.f;
    #pragma unroll
    for (int r = 0; r < 4; ++r){
      int n = nb + r;
      if (n < NN){
        size_t o = (size_t)n*ost + f;
        if (OUTBF){
          ((unsigned short*)OUTv)[o] = f2bf(acc[ft][r] + bv);
        } else {
          float* OUT = (float*)OUTv;
          if (ACCUM) OUT[o] += acc[ft][r];
          else       OUT[o] = acc[ft][r] + bv;
        }
      }
    }
  }
}

// ---------------- T[s,:] = sum over edges (src=s) of R[dst,:]  (bf16 in/out) ----------------
__global__ void k_esum(const int* __restrict__ rowstart, const int* __restrict__ sdst,
                       const unsigned short* __restrict__ R, unsigned short* __restrict__ T){
  int wg = (blockIdx.x*256 + threadIdx.x) >> 6;
  int lane = threadIdx.x & 63;
  if (wg >= NN) return;
  int e0 = rowstart[wg], e1 = rowstart[wg+1];
  float acc = 0.f;
  for (int e = e0; e < e1; ++e){
    int d = sdst[e];
    acc += bf2f(R[(size_t)d*FF + lane]);
  }
  T[(size_t)wg*FF + lane] = f2bf(acc);
}

// ---------------- softmax over C (axis 0) of w*U ----------------
__global__ void k_softmax(const float* __restrict__ U, const float* __restrict__ w,
                          float* __restrict__ fa){
  __shared__ float red[CC];
  int f = blockIdx.x, t = threadIdx.x; // 512 threads
  float v = w[t] * U[t*FF + f];
  red[t] = v; __syncthreads();
  for (int sft = 256; sft > 0; sft >>= 1){
    if (t < sft) red[t] = fmaxf(red[t], red[t+sft]);
    __syncthreads();
  }
  float mx = red[0]; __syncthreads();
  float e = expf(v - mx);
  red[t] = e; __syncthreads();
  for (int sft = 256; sft > 0; sft >>= 1){
    if (t < sft) red[t] += red[t+sft];
    __syncthreads();
  }
  float sum = red[0];
  fa[t*FF + f] = e / sum;
}

// ---------------- small GEMMs ----------------
__global__ void k_fe(const float* __restrict__ fa, const float* __restrict__ sem,
                     float* __restrict__ FE){
  int g = blockIdx.x, h = threadIdx.x; // 128
  float a = 0.f;
  for (int c = 0; c < CC; ++c) a += fa[c*FF + g] * sem[c*HH + h];
  FE[g*HH + h] = a;
}
__global__ void k_fw(const float* __restrict__ FE, const float* __restrict__ linW,
                     float* __restrict__ FW){
  int g = blockIdx.x, f = threadIdx.x; // 128, guard 100
  if (f >= 100) return;
  float a = 0.f;
  for (int h = 0; h < HH; ++h) a += FE[g*HH + h] * linW[(256 + h)*100 + f];
  FW[g*100 + f] = a;
}
__global__ void k_m(const float* __restrict__ sem, const float* __restrict__ fa,
                    const float* __restrict__ FW, const float* __restrict__ linW,
                    const float* __restrict__ w, float* __restrict__ M){
  int c = blockIdx.x, f = threadIdx.x; // 128, guard 100
  if (f >= 100) return;
  float a = 0.f;
  for (int h = 0; h < HH; ++h) a += sem[c*HH + h] * linW[(128 + h)*100 + f];
  for (int g = 0; g < FF; ++g) a += fa[c*FF + g] * FW[g*100 + f];
  M[c*100 + f] = w[c] * a;
}

// ---------------- edge scoring: pred[e] = X[a].X[b] (stride XST, pad cols = 0) ----------------
__global__ __launch_bounds__(256) void k_edot(const int* __restrict__ sedge,
                                              const float* __restrict__ X,
                                              float* __restrict__ out){
  int hw = (blockIdx.x*256 + threadIdx.x) >> 5;
  int hl = threadIdx.x & 31;
  if (hw >= ESN) return;
  int a = sedge[hw];
  int b = sedge[ESN + hw];
  float p = 0.f;
  if (hl < 28){
    float4 xa = *(const float4*)(X + (size_t)a*XST + hl*4);
    float4 xb = *(const float4*)(X + (size_t)b*XST + hl*4);
    p = xa.x*xb.x + xa.y*xb.y + xa.z*xb.z + xa.w*xb.w;
  }
  #pragma unroll
  for (int off = 16; off > 0; off >>= 1)
    p += __shfl_down(p, off, 32);
  if (hl == 0) out[hw] = p;
}

extern "C" void kernel_launch(void* const* d_in, const int* in_sizes, int n_in,
                              void* d_out, int out_size, void* d_ws, size_t ws_size,
                              hipStream_t stream){
  (void)in_sizes; (void)n_in; (void)out_size; (void)ws_size;
  const int*   lanef = (const int*)  d_in[0];
  const int*   typef = (const int*)  d_in[1];
  const int*   lenf  = (const int*)  d_in[2];
  const int*   nodef = (const int*)  d_in[3];
  const int*   adj   = (const int*)  d_in[4];
  const float* S     = (const float*)d_in[6];
  const int*   sedge = (const int*)  d_in[7];
  const float* WL    = (const float*)d_in[8];
  const float* WT    = (const float*)d_in[9];
  const float* WLen  = (const float*)d_in[10];
  const float* WNode = (const float*)d_in[11];
  const float* gcn   = (const float*)d_in[12];
  const float* linW  = (const float*)d_in[13];
  const float* linB  = (const float*)d_in[14];
  float* out = (float*)d_out;

  char* p = (char*)d_ws;
  auto alloc = [&](size_t bytes) -> void* {
    void* r = (void*)p;
    p += (bytes + 255) & ~(size_t)255;
    return r;
  };
  float* cs  = (float*)alloc(CC*4);
  float* w   = (float*)alloc(CC*4);
  float* SE  = (float*)alloc(CC*HH*4);
  float* sem = (float*)alloc(CC*HH*4);
  float* Q   = (float*)alloc(CC*FF*4);
  float* U   = (float*)alloc(CC*FF*4);
  float* fa  = (float*)alloc(CC*FF*4);
  float* FE  = (float*)alloc(FF*HH*4);
  float* FW  = (float*)alloc(FF*100*4);
  float* M   = (float*)alloc(CC*100*4);
  int* cnt      = (int*)alloc((size_t)NN*4);
  int* rowstart = (int*)alloc((size_t)(NN+1)*4);
  int* cursor   = (int*)alloc((size_t)NN*4);
  int* bsum     = (int*)alloc(512*4);
  int* boff     = (int*)alloc(512*4);
  int* sdst     = (int*)alloc((size_t)EE*4);
  unsigned short* S_bf = (unsigned short*)alloc((size_t)NN*CC*2);   // 102.4 MB
  unsigned short* rf2  = (unsigned short*)alloc((size_t)NN*256*2);  // 51.2 MB
  // Overlay region: [R_bf 12.8MB][T_bf 12.8MB][Ppart 32.8MB]; X (44.8MB) aliases its start.
  unsigned short* R_bf = (unsigned short*)alloc((size_t)NN*FF*2);
  unsigned short* T_bf = (unsigned short*)alloc((size_t)NN*FF*2);
  float* Ppart = (float*)alloc((size_t)NSPLIT*512*128*4);
  float* X = (float*)R_bf;   // written only after R/T/Ppart are dead

  const int NB = (NN + 255) / 256;   // 391

  k_init<<<NB, 256, 0, stream>>>(cs, cnt);
  k_prep<<<512, 128, 0, stream>>>(S, cs, S_bf);
  k_w<<<2, 256, 0, stream>>>(cs, w);
  k_rf<<<(NN*32)/256, 256, 0, stream>>>(lanef, typef, lenf, nodef, WL, WT, WLen, WNode, rf2);

  k_hist<<<(EE+255)/256, 256, 0, stream>>>(adj, cnt);
  k_scan_a<<<NB, 256, 0, stream>>>(cnt, rowstart, bsum);
  k_scan_b<<<1, 512, 0, stream>>>(bsum, boff, NB);
  k_scan_c<<<NB, 256, 0, stream>>>(rowstart, boff, cursor);
  k_scatter<<<(EE+255)/256, 256, 0, stream>>>(adj, cursor, sdst);

  // SE = S^T @ rf_hi (MFMA split-k + reduce)
  k_tgemm<128,256><<<NSPLIT, 1024, 0, stream>>>(S_bf, rf2, Ppart);
  k_reduce<128><<<(512*128)/256, 256, 0, stream>>>(Ppart, SE);
  k_sepq<<<CC, 64, 0, stream>>>(SE, w, gcn, sem, Q);
  // R = S @ Q (bf16 out)
  k_mgemm<4,512,64,511,false,false,true><<<NB, 1024, 0, stream>>>(S_bf, Q, nullptr, R_bf, FF);
  k_esum<<<(NN*64)/256, 256, 0, stream>>>(rowstart, sdst, R_bf, T_bf);
  // U = S^T @ T
  k_tgemm<64,64><<<NSPLIT, 1024, 0, stream>>>(S_bf, T_bf, Ppart);
  k_reduce<64><<<(512*64)/256, 256, 0, stream>>>(Ppart, U);
  k_softmax<<<FF, 512, 0, stream>>>(U, w, fa);
  k_fe<<<FF, 128, 0, stream>>>(fa, sem, FE);
  k_fw<<<FF, 128, 0, stream>>>(FE, linW, FW);
  k_m<<<CC, 128, 0, stream>>>(sem, fa, FW, linW, w, M);

  // X = S@M + bias  (K=512), then X += [rf_hi|rf_lo]@W1 (K=256, rows k&127)
  k_mgemm<7,512,100,511,false,true ,false><<<NB, 1024, 0, stream>>>(S_bf, M, linB, X, XST);
  k_mgemm<7,256,100,127,true ,false,false><<<NB, 1024, 0, stream>>>(rf2, linW, nullptr, X, XST);

  k_edot<<<(ESN*32)/256, 256, 0, stream>>>(sedge, X, out);
}

// Round 4
// 982.329 us; speedup vs baseline: 2.8235x; 1.0820x over previous
//
#include <hip/hip_runtime.h>
#include <cstddef>
#include <cstdint>

#define NN  100000
#define CC  512
#define FF  64
#define HH  128
#define EE  1600000
#define ESN 1000000
#define XST 112      // padded X row stride (100 -> 112), pad cols are exactly 0
#define NSPLIT 125   // k-split blocks for k_tgemm
#define KPB 800      // k-rows per block (125*800 = 100000 exactly, 800%32==0)

typedef __attribute__((ext_vector_type(8))) short s16x8;
typedef __attribute__((ext_vector_type(4))) float f32x4;

__device__ __forceinline__ unsigned short f2bf(float x){
  unsigned u = __builtin_bit_cast(unsigned, x);
  unsigned r = u + 0x7fffu + ((u >> 16) & 1u);
  return (unsigned short)(r >> 16);
}
__device__ __forceinline__ float bf2f(unsigned short h){
  return __builtin_bit_cast(float, (unsigned)h << 16);
}

// ---------------- init: zero accumulators ----------------
__global__ void k_init(float* cs, int* cnt){
  int i = blockIdx.x*256 + threadIdx.x;
  if (i < CC) cs[i] = 0.f;
  if (i < NN) cnt[i] = 0;
}

// ---------------- column sums of S + cast S -> bf16 (8-deep MLP unroll) ----------------
#define PREP_G 1024
__global__ __launch_bounds__(128) void k_prep(const float* __restrict__ S, float* __restrict__ cs,
                                              unsigned short* __restrict__ S_bf){
  int t = threadIdx.x;            // 128 threads, 4 cols each
  int c = t * 4;
  float a0=0.f, a1=0.f, a2=0.f, a3=0.f;
  for (int r0 = blockIdx.x; r0 < NN; r0 += PREP_G*8){
    float4 v[8];
    #pragma unroll
    for (int u = 0; u < 8; ++u){
      int r = r0 + u*PREP_G;
      if (r < NN) v[u] = *(const float4*)(S + (size_t)r*CC + c);
    }
    #pragma unroll
    for (int u = 0; u < 8; ++u){
      int r = r0 + u*PREP_G;
      if (r < NN){
        a0 += v[u].x; a1 += v[u].y; a2 += v[u].z; a3 += v[u].w;
        ushort4 b;
        b.x = f2bf(v[u].x); b.y = f2bf(v[u].y); b.z = f2bf(v[u].z); b.w = f2bf(v[u].w);
        *(ushort4*)(S_bf + (size_t)r*CC + c) = b;
      }
    }
  }
  atomicAdd(&cs[c+0], a0); atomicAdd(&cs[c+1], a1);
  atomicAdd(&cs[c+2], a2); atomicAdd(&cs[c+3], a3);
}

__global__ void k_w(const float* __restrict__ cs, float* __restrict__ w){
  int c = blockIdx.x*256 + threadIdx.x;
  if (c < CC){
    float d = cs[c] - 1.f;
    if (d < 0.f) d = 0.f;
    w[c] = 1.f / (d + 1.f);
  }
}

// ---------------- raw_feat build -> rf2 = [hi(128) | lo(128)] bf16 ----------------
__global__ void k_rf(const int* __restrict__ lanef, const int* __restrict__ typef,
                     const int* __restrict__ lenf, const int* __restrict__ nodef,
                     const float* __restrict__ WL, const float* __restrict__ WT,
                     const float* __restrict__ WLen, const float* __restrict__ WNode,
                     unsigned short* __restrict__ rf2){
  int gid = blockIdx.x*256 + threadIdx.x;
  int n = gid >> 5, q = gid & 31;
  if (n >= NN) return;
  int col = (q & 7) * 4;
  const float* src;
  int sel = q >> 3;
  if (sel == 0)      src = WL   + (size_t)lanef[n]*32 + col;
  else if (sel == 1) src = WT   + (size_t)typef[n]*32 + col;
  else if (sel == 2) src = WLen + (size_t)lenf[n]*32 + col;
  else               src = WNode+ (size_t)nodef[n]*32 + col;
  float4 v = *(const float4*)src;
  ushort4 h, lo;
  h.x = f2bf(v.x); lo.x = f2bf(v.x - bf2f(h.x));
  h.y = f2bf(v.y); lo.y = f2bf(v.y - bf2f(h.y));
  h.z = f2bf(v.z); lo.z = f2bf(v.z - bf2f(h.z));
  h.w = f2bf(v.w); lo.w = f2bf(v.w - bf2f(h.w));
  *(ushort4*)(rf2 + (size_t)n*256 + q*4) = h;
  *(ushort4*)(rf2 + (size_t)n*256 + 128 + q*4) = lo;
}

// ---------------- edge counting sort ----------------
__global__ void k_hist(const int* __restrict__ adj, int* __restrict__ cnt){
  int e = blockIdx.x*256 + threadIdx.x;
  if (e < EE) atomicAdd(&cnt[adj[e]], 1);
}
__global__ void k_scan_a(const int* __restrict__ cnt, int* __restrict__ loc, int* __restrict__ bsum){
  __shared__ int sh[256];
  int b = blockIdx.x, t = threadIdx.x;
  int i = b*256 + t;
  int v = (i < NN) ? cnt[i] : 0;
  sh[t] = v; __syncthreads();
  for (int off = 1; off < 256; off <<= 1){
    int x = (t >= off) ? sh[t-off] : 0;
    __syncthreads();
    sh[t] += x;
    __syncthreads();
  }
  if (i < NN) loc[i] = sh[t] - v;
  if (t == 255) bsum[b] = sh[t];
}
__global__ void k_scan_b(const int* __restrict__ bsum, int* __restrict__ boff, int nb){
  __shared__ int sh[512];
  int t = threadIdx.x;
  int v = (t < nb) ? bsum[t] : 0;
  sh[t] = v; __syncthreads();
  for (int off = 1; off < 512; off <<= 1){
    int x = (t >= off) ? sh[t-off] : 0;
    __syncthreads();
    sh[t] += x;
    __syncthreads();
  }
  if (t < nb) boff[t] = sh[t] - v;
}
__global__ void k_scan_c(int* __restrict__ rowstart, const int* __restrict__ boff, int* __restrict__ cursor){
  int i = blockIdx.x*256 + threadIdx.x;
  if (i < NN){
    int v = rowstart[i] + boff[i >> 8];
    rowstart[i] = v; cursor[i] = v;
  }
  if (i == NN) rowstart[NN] = EE;
}
__global__ void k_scatter(const int* __restrict__ adj, int* __restrict__ cursor, int* __restrict__ sdst){
  int e = blockIdx.x*256 + threadIdx.x;
  if (e < EE){
    int s = adj[e], d = adj[EE + e];
    int pos = atomicAdd(&cursor[s], 1);
    sdst[pos] = d;
  }
}

// ------- MFMA split-k GEMM: P[b] = S[b-slice]^T @ V[b-slice]  ([512, F] partials) -------
template<int F, int VST>
__global__ __launch_bounds__(1024) void k_tgemm(const unsigned short* __restrict__ Sb,
                                                const unsigned short* __restrict__ V,
                                                float* __restrict__ P){
  __shared__ unsigned short S_t[512*40];
  __shared__ unsigned short V_t[F*40];
  constexpr int HT = F/16;
  const int t = threadIdx.x;
  const int lane = t & 63, wid = t >> 6;   // 16 waves
  const int cb = lane & 15, q = lane >> 4;
  const int n0 = blockIdx.x * KPB;
  const int n1 = min(n0 + KPB, NN);
  const int scg = t >> 4;                  // 0..63 (c-octet)
  const int sp  = t & 15;                  // row-pair
  f32x4 acc[2][HT];
  #pragma unroll
  for (int a=0;a<2;a++)
    #pragma unroll
    for (int b=0;b<HT;b++) acc[a][b] = (f32x4){0.f,0.f,0.f,0.f};

  for (int rb = n0; rb < n1; rb += 32){
    __syncthreads();
    { // stage S_t[c][k] for k-rows rb..rb+31
      int na = rb + 2*sp, nb2 = na + 1;
      s16x8 va = (s16x8){0,0,0,0,0,0,0,0}, vb = va;
      if (na  < n1) va = *(const s16x8*)(Sb + (size_t)na *512 + scg*8);
      if (nb2 < n1) vb = *(const s16x8*)(Sb + (size_t)nb2*512 + scg*8);
      int k2 = 2*sp;
      #pragma unroll
      for (int m = 0; m < 8; ++m){
        unsigned pack = (unsigned)(unsigned short)va[m] | ((unsigned)(unsigned short)vb[m] << 16);
        *(unsigned*)&S_t[(scg*8 + m)*40 + k2] = pack;
      }
    }
    if (t < 2*F){ // stage V_t[h][k]
      int vcg = t >> 4;      // 0..F/8-1
      int vp  = t & 15;
      int na = rb + 2*vp, nb2 = na + 1;
      s16x8 va = (s16x8){0,0,0,0,0,0,0,0}, vb = va;
      if (na  < n1) va = *(const s16x8*)(V + (size_t)na *VST + vcg*8);
      if (nb2 < n1) vb = *(const s16x8*)(V + (size_t)nb2*VST + vcg*8);
      int k2 = 2*vp;
      #pragma unroll
      for (int m = 0; m < 8; ++m){
        unsigned pack = (unsigned)(unsigned short)va[m] | ((unsigned)(unsigned short)vb[m] << 16);
        *(unsigned*)&V_t[(vcg*8 + m)*40 + k2] = pack;
      }
    }
    __syncthreads();
    s16x8 af[2];
    #pragma unroll
    for (int ct = 0; ct < 2; ++ct){
      int c = wid*32 + ct*16 + cb;
      af[ct] = *(const s16x8*)&S_t[c*40 + q*8];
    }
    #pragma unroll
    for (int ht = 0; ht < HT; ++ht){
      s16x8 bf = *(const s16x8*)&V_t[(ht*16 + cb)*40 + q*8];
      #pragma unroll
      for (int ct = 0; ct < 2; ++ct)
        acc[ct][ht] = __builtin_amdgcn_mfma_f32_16x16x32_bf16(af[ct], bf, acc[ct][ht], 0, 0, 0);
    }
  }
  float* Pb = P + (size_t)blockIdx.x * 512 * F;
  #pragma unroll
  for (int ct = 0; ct < 2; ++ct)
    #pragma unroll
    for (int ht = 0; ht < HT; ++ht)
      #pragma unroll
      for (int r = 0; r < 4; ++r)
        Pb[(wid*32 + ct*16 + q*4 + r)*F + ht*16 + cb] = acc[ct][ht][r];
}

template<int F>
__global__ void k_reduce(const float* __restrict__ P, float* __restrict__ OUT){
  int i = blockIdx.x*256 + threadIdx.x;    // < 512*F
  float s = 0.f;
  for (int b = 0; b < NSPLIT; ++b) s += P[(size_t)b*(512*F) + i];
  OUT[i] = s;
}

// ---- struct_emb = w*SE ; Q = w * (struct_emb @ gcn_W) ----
__global__ void k_sepq(const float* __restrict__ SE, const float* __restrict__ w,
                       const float* __restrict__ gcn, float* __restrict__ sem,
                       float* __restrict__ Q){
  __shared__ float row[HH];
  int c = blockIdx.x, f = threadIdx.x; // 64 threads
  float wc = w[c];
  for (int h = f; h < HH; h += 64){
    float v = wc * SE[c*HH + h];
    row[h] = v;
    sem[c*HH + h] = v;
  }
  __syncthreads();
  float p = 0.f;
  for (int h = 0; h < HH; ++h) p += row[h] * gcn[h*FF + f];
  Q[c*FF + f] = wc * p;
}

// ---------------- MFMA GEMM: OUT[N, FT*16] (=|+=) A_bf16[N,K] @ B[K,F] ----------------
template<int FT, int K, int FSRC, int KSRCM, bool ACCUM, bool BIAS, bool OUTBF>
__global__ __launch_bounds__(1024) void k_mgemm(const unsigned short* __restrict__ A,
                                                const float* __restrict__ Bsrc,
                                                const float* __restrict__ bias,
                                                void* __restrict__ OUTv, int ost){
  __shared__ unsigned short Bt[FT*16*K];
  const int t = threadIdx.x;
  for (int i = t; i < FT*16*K; i += 1024){
    int f = i / K, k = i - f*K;
    float v = (f < FSRC) ? Bsrc[(size_t)(k & KSRCM)*FSRC + f] : 0.f;
    Bt[f*K + ((((k >> 3) ^ (f & 7)) << 3) | (k & 7))] = f2bf(v);
  }
  __syncthreads();
  const int lane = t & 63;
  const int wid  = t >> 6;           // 0..15
  const int cb   = lane & 15;
  const int q    = lane >> 4;
  const int s    = cb & 7;
  const int arow = min(blockIdx.x*256 + wid*16 + cb, NN-1);
  const unsigned short* ap = A + (size_t)arow*K + q*8;

  f32x4 acc[FT];
  #pragma unroll
  for (int ft = 0; ft < FT; ++ft) acc[ft] = (f32x4){0.f,0.f,0.f,0.f};

  #pragma unroll 2
  for (int kt = 0; kt < K/32; ++kt){
    s16x8 a = *(const s16x8*)(ap + kt*32);
    int boff = (((kt*4 + q) ^ s) << 3);
    #pragma unroll
    for (int ft = 0; ft < FT; ++ft){
      s16x8 b = *(const s16x8*)&Bt[(ft*16 + cb)*K + boff];
      acc[ft] = __builtin_amdgcn_mfma_f32_16x16x32_bf16(a, b, acc[ft], 0, 0, 0);
    }
  }

  const int nb = blockIdx.x*256 + wid*16 + q*4;
  #pragma unroll
  for (int ft = 0; ft < FT; ++ft){
    int f = ft*16 + cb;
    float bv = 0.f;
    if (BIAS) bv = (f < FSRC) ? bias[f] : 0.f;
    #pragma unroll
    for (int r = 0; r < 4; ++r){
      int n = nb + r;
      if (n < NN){
        size_t o = (size_t)n*ost + f;
        if (OUTBF){
          ((unsigned short*)OUTv)[o] = f2bf(acc[ft][r] + bv);
        } else {
          float* OUT = (float*)OUTv;
          if (ACCUM) OUT[o] += acc[ft][r];
          else       OUT[o] = acc[ft][r] + bv;
        }
      }
    }
  }
}

// ------- T[s,:] = sum over edges (src=s) of R[dst,:] (bf16 in/out, 4-deep MLP) -------
__global__ void k_esum(const int* __restrict__ rowstart, const int* __restrict__ sdst,
                       const unsigned short* __restrict__ R, unsigned short* __restrict__ T){
  int wg = (blockIdx.x*256 + threadIdx.x) >> 6;
  int lane = threadIdx.x & 63;
  if (wg >= NN) return;
  int e0 = rowstart[wg], e1 = rowstart[wg+1];
  float acc = 0.f;
  int e = e0;
  for (; e + 3 < e1; e += 4){
    int d0 = sdst[e], d1 = sdst[e+1], d2 = sdst[e+2], d3 = sdst[e+3];
    unsigned short r0 = R[(size_t)d0*FF + lane];
    unsigned short r1 = R[(size_t)d1*FF + lane];
    unsigned short r2 = R[(size_t)d2*FF + lane];
    unsigned short r3 = R[(size_t)d3*FF + lane];
    acc += bf2f(r0) + bf2f(r1) + bf2f(r2) + bf2f(r3);
  }
  for (; e < e1; ++e){
    int d = sdst[e];
    acc += bf2f(R[(size_t)d*FF + lane]);
  }
  T[(size_t)wg*FF + lane] = f2bf(acc);
}

// ---------------- softmax over C (axis 0) of w*U ----------------
__global__ void k_softmax(const float* __restrict__ U, const float* __restrict__ w,
                          float* __restrict__ fa){
  __shared__ float red[CC];
  int f = blockIdx.x, t = threadIdx.x; // 512 threads
  float v = w[t] * U[t*FF + f];
  red[t] = v; __syncthreads();
  for (int sft = 256; sft > 0; sft >>= 1){
    if (t < sft) red[t] = fmaxf(red[t], red[t+sft]);
    __syncthreads();
  }
  float mx = red[0]; __syncthreads();
  float e = expf(v - mx);
  red[t] = e; __syncthreads();
  for (int sft = 256; sft > 0; sft >>= 1){
    if (t < sft) red[t] += red[t+sft];
    __syncthreads();
  }
  float sum = red[0];
  fa[t*FF + f] = e / sum;
}

// ---------------- small GEMMs ----------------
__global__ void k_fe(const float* __restrict__ fa, const float* __restrict__ sem,
                     float* __restrict__ FE){
  int g = blockIdx.x, h = threadIdx.x; // 128
  float a = 0.f;
  for (int c = 0; c < CC; ++c) a += fa[c*FF + g] * sem[c*HH + h];
  FE[g*HH + h] = a;
}
__global__ void k_fw(const float* __restrict__ FE, const float* __restrict__ linW,
                     float* __restrict__ FW){
  int g = blockIdx.x, f = threadIdx.x; // 128, guard 100
  if (f >= 100) return;
  float a = 0.f;
  for (int h = 0; h < HH; ++h) a += FE[g*HH + h] * linW[(256 + h)*100 + f];
  FW[g*100 + f] = a;
}
__global__ void k_m(const float* __restrict__ sem, const float* __restrict__ fa,
                    const float* __restrict__ FW, const float* __restrict__ linW,
                    const float* __restrict__ w, float* __restrict__ M){
  int c = blockIdx.x, f = threadIdx.x; // 128, guard 100
  if (f >= 100) return;
  float a = 0.f;
  for (int h = 0; h < HH; ++h) a += sem[c*HH + h] * linW[(128 + h)*100 + f];
  for (int g = 0; g < FF; ++g) a += fa[c*FF + g] * FW[g*100 + f];
  M[c*100 + f] = w[c] * a;
}

// ---------------- edge scoring: pred[e] = X[a].X[b] (stride XST, pad cols = 0) ----------------
__global__ __launch_bounds__(256) void k_edot(const int* __restrict__ sedge,
                                              const float* __restrict__ X,
                                              float* __restrict__ out){
  int hw = (blockIdx.x*256 + threadIdx.x) >> 5;
  int hl = threadIdx.x & 31;
  if (hw >= ESN) return;
  int a = sedge[hw];
  int b = sedge[ESN + hw];
  float p = 0.f;
  if (hl < 28){
    float4 xa = *(const float4*)(X + (size_t)a*XST + hl*4);
    float4 xb = *(const float4*)(X + (size_t)b*XST + hl*4);
    p = xa.x*xb.x + xa.y*xb.y + xa.z*xb.z + xa.w*xb.w;
  }
  #pragma unroll
  for (int off = 16; off > 0; off >>= 1)
    p += __shfl_down(p, off, 32);
  if (hl == 0) out[hw] = p;
}

extern "C" void kernel_launch(void* const* d_in, const int* in_sizes, int n_in,
                              void* d_out, int out_size, void* d_ws, size_t ws_size,
                              hipStream_t stream){
  (void)in_sizes; (void)n_in; (void)out_size; (void)ws_size;
  const int*   lanef = (const int*)  d_in[0];
  const int*   typef = (const int*)  d_in[1];
  const int*   lenf  = (const int*)  d_in[2];
  const int*   nodef = (const int*)  d_in[3];
  const int*   adj   = (const int*)  d_in[4];
  const float* S     = (const float*)d_in[6];
  const int*   sedge = (const int*)  d_in[7];
  const float* WL    = (const float*)d_in[8];
  const float* WT    = (const float*)d_in[9];
  const float* WLen  = (const float*)d_in[10];
  const float* WNode = (const float*)d_in[11];
  const float* gcn   = (const float*)d_in[12];
  const float* linW  = (const float*)d_in[13];
  const float* linB  = (const float*)d_in[14];
  float* out = (float*)d_out;

  char* p = (char*)d_ws;
  auto alloc = [&](size_t bytes) -> void* {
    void* r = (void*)p;
    p += (bytes + 255) & ~(size_t)255;
    return r;
  };
  float* cs  = (float*)alloc(CC*4);
  float* w   = (float*)alloc(CC*4);
  float* SE  = (float*)alloc(CC*HH*4);
  float* sem = (float*)alloc(CC*HH*4);
  float* Q   = (float*)alloc(CC*FF*4);
  float* U   = (float*)alloc(CC*FF*4);
  float* fa  = (float*)alloc(CC*FF*4);
  float* FE  = (float*)alloc(FF*HH*4);
  float* FW  = (float*)alloc(FF*100*4);
  float* M   = (float*)alloc(CC*100*4);
  int* cnt      = (int*)alloc((size_t)NN*4);
  int* rowstart = (int*)alloc((size_t)(NN+1)*4);
  int* cursor   = (int*)alloc((size_t)NN*4);
  int* bsum     = (int*)alloc(512*4);
  int* boff     = (int*)alloc(512*4);
  int* sdst     = (int*)alloc((size_t)EE*4);
  unsigned short* S_bf = (unsigned short*)alloc((size_t)NN*CC*2);   // 102.4 MB
  unsigned short* rf2  = (unsigned short*)alloc((size_t)NN*256*2);  // 51.2 MB
  // Overlay region: [R_bf 12.8MB][T_bf 12.8MB][Ppart 32.8MB]; X (44.8MB) aliases its start.
  unsigned short* R_bf = (unsigned short*)alloc((size_t)NN*FF*2);
  unsigned short* T_bf = (unsigned short*)alloc((size_t)NN*FF*2);
  float* Ppart = (float*)alloc((size_t)NSPLIT*512*128*4);
  float* X = (float*)R_bf;   // written only after R/T/Ppart are dead

  const int NB = (NN + 255) / 256;   // 391

  k_init<<<NB, 256, 0, stream>>>(cs, cnt);
  k_prep<<<PREP_G, 128, 0, stream>>>(S, cs, S_bf);
  k_w<<<2, 256, 0, stream>>>(cs, w);
  k_rf<<<(NN*32)/256, 256, 0, stream>>>(lanef, typef, lenf, nodef, WL, WT, WLen, WNode, rf2);

  k_hist<<<(EE+255)/256, 256, 0, stream>>>(adj, cnt);
  k_scan_a<<<NB, 256, 0, stream>>>(cnt, rowstart, bsum);
  k_scan_b<<<1, 512, 0, stream>>>(bsum, boff, NB);
  k_scan_c<<<NB, 256, 0, stream>>>(rowstart, boff, cursor);
  k_scatter<<<(EE+255)/256, 256, 0, stream>>>(adj, cursor, sdst);

  // SE = S^T @ rf_hi (MFMA split-k + reduce)
  k_tgemm<128,256><<<NSPLIT, 1024, 0, stream>>>(S_bf, rf2, Ppart);
  k_reduce<128><<<(512*128)/256, 256, 0, stream>>>(Ppart, SE);
  k_sepq<<<CC, 64, 0, stream>>>(SE, w, gcn, sem, Q);
  // R = S @ Q (bf16 out)
  k_mgemm<4,512,64,511,false,false,true><<<NB, 1024, 0, stream>>>(S_bf, Q, nullptr, R_bf, FF);
  k_esum<<<(NN*64)/256, 256, 0, stream>>>(rowstart, sdst, R_bf, T_bf);
  // U = S^T @ T
  k_tgemm<64,64><<<NSPLIT, 1024, 0, stream>>>(S_bf, T_bf, Ppart);
  k_reduce<64><<<(512*64)/256, 256, 0, stream>>>(Ppart, U);
  k_softmax<<<FF, 512, 0, stream>>>(U, w, fa);
  k_fe<<<FF, 128, 0, stream>>>(fa, sem, FE);
  k_fw<<<FF, 128, 0, stream>>>(FE, linW, FW);
  k_m<<<CC, 128, 0, stream>>>(sem, fa, FW, linW, w, M);

  // X = S@M + bias  (K=512), then X += [rf_hi|rf_lo]@W1 (K=256, rows k&127)
  k_mgemm<7,512,100,511,false,true ,false><<<NB, 1024, 0, stream>>>(S_bf, M, linB, X, XST);
  k_mgemm<7,256,100,127,true ,false,false><<<NB, 1024, 0, stream>>>(rf2, linW, nullptr, X, XST);

  k_edot<<<(ESN*32)/256, 256, 0, stream>>>(sedge, X, out);
}

// Round 5
// 888.397 us; speedup vs baseline: 3.1221x; 1.1057x over previous
//
#include <hip/hip_runtime.h>
#include <cstddef>
#include <cstdint>

#define NN  100000
#define CC  512
#define FF  64
#define HH  128
#define EE  1600000
#define ESN 1000000
#define XST 112      // padded X row stride (100 -> 112), pad cols are exactly 0
#define NSPLIT 200   // k-split blocks for k_tgemm (200*500 = 100000 exactly)
#define KPB 500      // k-rows per block
#define PREP_B 625   // k_prep blocks: 1250 row streams x 80 rows, 100000 = 1250*8*10

typedef __attribute__((ext_vector_type(8))) short s16x8;
typedef __attribute__((ext_vector_type(4))) float f32x4;

__device__ __forceinline__ unsigned short f2bf(float x){
  unsigned u = __builtin_bit_cast(unsigned, x);
  unsigned r = u + 0x7fffu + ((u >> 16) & 1u);
  return (unsigned short)(r >> 16);
}
__device__ __forceinline__ float bf2f(unsigned short h){
  return __builtin_bit_cast(float, (unsigned)h << 16);
}

// ---------------- init: zero edge counters ----------------
__global__ void k_init(int* cnt){
  int i = blockIdx.x*256 + threadIdx.x;
  if (i < NN) cnt[i] = 0;
}

// ------- column partial sums of S + cast S -> bf16 (8-deep, guard-free MLP) -------
// 1250 row-streams (stream = blockIdx.x*2 + t/128), stride 1250, 80 rows each.
__global__ __launch_bounds__(256) void k_prep(const float* __restrict__ S,
                                              float* __restrict__ csb,
                                              unsigned short* __restrict__ S_bf){
  __shared__ float4 sh4[256];
  const int t = threadIdx.x;
  const int cq = t & 127;
  const int c  = cq * 4;
  const int rs = blockIdx.x*2 + (t >> 7);    // 0..1249
  float a0=0.f, a1=0.f, a2=0.f, a3=0.f;
  #pragma unroll 1
  for (int it = 0; it < 10; ++it){
    float4 v[8];
    #pragma unroll
    for (int u = 0; u < 8; ++u){
      int r = rs + (it*8 + u)*1250;
      v[u] = *(const float4*)(S + (size_t)r*CC + c);
    }
    #pragma unroll
    for (int u = 0; u < 8; ++u){
      int r = rs + (it*8 + u)*1250;
      a0 += v[u].x; a1 += v[u].y; a2 += v[u].z; a3 += v[u].w;
      ushort4 b;
      b.x = f2bf(v[u].x); b.y = f2bf(v[u].y); b.z = f2bf(v[u].z); b.w = f2bf(v[u].w);
      *(ushort4*)(S_bf + (size_t)r*CC + c) = b;
    }
  }
  sh4[t] = (float4){a0, a1, a2, a3};
  __syncthreads();
  if (t < 128){
    float4 o = sh4[t + 128];
    a0 += o.x; a1 += o.y; a2 += o.z; a3 += o.w;
    *(float4*)(csb + (size_t)blockIdx.x*512 + c) = (float4){a0, a1, a2, a3};
  }
}

// ---- w[c] = 1/(relu(colsum-1)+1), reducing csb[625][512] ----
__global__ void k_w(const float* __restrict__ csb, float* __restrict__ w){
  int t = threadIdx.x;   // 512 threads, 1 block
  float s0=0.f, s1=0.f, s2=0.f, s3=0.f, s4=0.f;
  for (int b = 0; b < 625; b += 5){
    s0 += csb[(size_t)(b+0)*512 + t];
    s1 += csb[(size_t)(b+1)*512 + t];
    s2 += csb[(size_t)(b+2)*512 + t];
    s3 += csb[(size_t)(b+3)*512 + t];
    s4 += csb[(size_t)(b+4)*512 + t];
  }
  float s = ((s0+s1)+(s2+s3)) + s4;
  float d = s - 1.f;
  if (d < 0.f) d = 0.f;
  w[t] = 1.f / (d + 1.f);
}

// ---------------- raw_feat build -> rf2 = [hi(128) | lo(128)] bf16 ----------------
__global__ void k_rf(const int* __restrict__ lanef, const int* __restrict__ typef,
                     const int* __restrict__ lenf, const int* __restrict__ nodef,
                     const float* __restrict__ WL, const float* __restrict__ WT,
                     const float* __restrict__ WLen, const float* __restrict__ WNode,
                     unsigned short* __restrict__ rf2){
  int gid = blockIdx.x*256 + threadIdx.x;
  int n = gid >> 5, q = gid & 31;
  if (n >= NN) return;
  int col = (q & 7) * 4;
  const float* src;
  int sel = q >> 3;
  if (sel == 0)      src = WL   + (size_t)lanef[n]*32 + col;
  else if (sel == 1) src = WT   + (size_t)typef[n]*32 + col;
  else if (sel == 2) src = WLen + (size_t)lenf[n]*32 + col;
  else               src = WNode+ (size_t)nodef[n]*32 + col;
  float4 v = *(const float4*)src;
  ushort4 h, lo;
  h.x = f2bf(v.x); lo.x = f2bf(v.x - bf2f(h.x));
  h.y = f2bf(v.y); lo.y = f2bf(v.y - bf2f(h.y));
  h.z = f2bf(v.z); lo.z = f2bf(v.z - bf2f(h.z));
  h.w = f2bf(v.w); lo.w = f2bf(v.w - bf2f(h.w));
  *(ushort4*)(rf2 + (size_t)n*256 + q*4) = h;
  *(ushort4*)(rf2 + (size_t)n*256 + 128 + q*4) = lo;
}

// ---------------- edge counting sort ----------------
__global__ void k_hist(const int* __restrict__ adj, int* __restrict__ cnt){
  int e = blockIdx.x*256 + threadIdx.x;
  if (e < EE) atomicAdd(&cnt[adj[e]], 1);
}
__global__ void k_scan_a(const int* __restrict__ cnt, int* __restrict__ loc, int* __restrict__ bsum){
  __shared__ int sh[256];
  int b = blockIdx.x, t = threadIdx.x;
  int i = b*256 + t;
  int v = (i < NN) ? cnt[i] : 0;
  sh[t] = v; __syncthreads();
  for (int off = 1; off < 256; off <<= 1){
    int x = (t >= off) ? sh[t-off] : 0;
    __syncthreads();
    sh[t] += x;
    __syncthreads();
  }
  if (i < NN) loc[i] = sh[t] - v;
  if (t == 255) bsum[b] = sh[t];
}
__global__ void k_scan_b(const int* __restrict__ bsum, int* __restrict__ boff, int nb){
  __shared__ int sh[512];
  int t = threadIdx.x;
  int v = (t < nb) ? bsum[t] : 0;
  sh[t] = v; __syncthreads();
  for (int off = 1; off < 512; off <<= 1){
    int x = (t >= off) ? sh[t-off] : 0;
    __syncthreads();
    sh[t] += x;
    __syncthreads();
  }
  if (t < nb) boff[t] = sh[t] - v;
}
__global__ void k_scan_c(int* __restrict__ rowstart, const int* __restrict__ boff, int* __restrict__ cursor){
  int i = blockIdx.x*256 + threadIdx.x;
  if (i < NN){
    int v = rowstart[i] + boff[i >> 8];
    rowstart[i] = v; cursor[i] = v;
  }
  if (i == NN) rowstart[NN] = EE;
}
__global__ void k_scatter(const int* __restrict__ adj, int* __restrict__ cursor, int* __restrict__ sdst){
  int e = blockIdx.x*256 + threadIdx.x;
  if (e < EE){
    int s = adj[e], d = adj[EE + e];
    int pos = atomicAdd(&cursor[s], 1);
    sdst[pos] = d;
  }
}

// ------- MFMA split-k GEMM: P[b] = S[b-slice]^T @ V[b-slice]  ([512, F] partials) -------
// Staged transposed into LDS; 8-row-group sigma shift (+64B) makes staging writes 2-way.
template<int F, int VST>
__global__ __launch_bounds__(1024) void k_tgemm(const unsigned short* __restrict__ Sb,
                                                const unsigned short* __restrict__ V,
                                                float* __restrict__ P){
  __shared__ unsigned short S_t[512*40 + 32];
  __shared__ unsigned short V_t[F*40 + 32];
  constexpr int HT = F/16;
  const int t = threadIdx.x;
  const int lane = t & 63, wid = t >> 6;   // 16 waves
  const int cb = lane & 15, q = lane >> 4;
  const int sig32 = ((cb >> 3) & 1) * 32;  // read-side sigma (row>>3 parity)
  const int n0 = blockIdx.x * KPB;
  const int n1 = min(n0 + KPB, NN);
  const int scg = t >> 4;                  // 0..63 (c-octet)
  const int sp  = t & 15;                  // row-pair
  const int wsig = (scg & 1) * 32;         // write-side sigma
  f32x4 acc[2][HT];
  #pragma unroll
  for (int a=0;a<2;a++)
    #pragma unroll
    for (int b=0;b<HT;b++) acc[a][b] = (f32x4){0.f,0.f,0.f,0.f};

  for (int rb = n0; rb < n1; rb += 32){
    __syncthreads();
    { // stage S_t[c][k] for k-rows rb..rb+31
      int na = rb + 2*sp, nb2 = na + 1;
      s16x8 va = (s16x8){0,0,0,0,0,0,0,0}, vb = va;
      if (na  < n1) va = *(const s16x8*)(Sb + (size_t)na *512 + scg*8);
      if (nb2 < n1) vb = *(const s16x8*)(Sb + (size_t)nb2*512 + scg*8);
      int k2 = 2*sp;
      #pragma unroll
      for (int m = 0; m < 8; ++m){
        unsigned pack = (unsigned)(unsigned short)va[m] | ((unsigned)(unsigned short)vb[m] << 16);
        *(unsigned*)&S_t[(scg*8 + m)*40 + wsig + k2] = pack;
      }
    }
    if (t < 2*F){ // stage V_t[h][k]
      int vcg = t >> 4;      // 0..F/8-1
      int vp  = t & 15;
      int vsig = (vcg & 1) * 32;
      int na = rb + 2*vp, nb2 = na + 1;
      s16x8 va = (s16x8){0,0,0,0,0,0,0,0}, vb = va;
      if (na  < n1) va = *(const s16x8*)(V + (size_t)na *VST + vcg*8);
      if (nb2 < n1) vb = *(const s16x8*)(V + (size_t)nb2*VST + vcg*8);
      int k2 = 2*vp;
      #pragma unroll
      for (int m = 0; m < 8; ++m){
        unsigned pack = (unsigned)(unsigned short)va[m] | ((unsigned)(unsigned short)vb[m] << 16);
        *(unsigned*)&V_t[(vcg*8 + m)*40 + vsig + k2] = pack;
      }
    }
    __syncthreads();
    s16x8 af[2];
    #pragma unroll
    for (int ct = 0; ct < 2; ++ct){
      int c = wid*32 + ct*16 + cb;
      af[ct] = *(const s16x8*)&S_t[c*40 + sig32 + q*8];
    }
    #pragma unroll
    for (int ht = 0; ht < HT; ++ht){
      s16x8 bf = *(const s16x8*)&V_t[(ht*16 + cb)*40 + sig32 + q*8];
      #pragma unroll
      for (int ct = 0; ct < 2; ++ct)
        acc[ct][ht] = __builtin_amdgcn_mfma_f32_16x16x32_bf16(af[ct], bf, acc[ct][ht], 0, 0, 0);
    }
  }
  float* Pb = P + (size_t)blockIdx.x * 512 * F;
  #pragma unroll
  for (int ct = 0; ct < 2; ++ct)
    #pragma unroll
    for (int ht = 0; ht < HT; ++ht)
      #pragma unroll
      for (int r = 0; r < 4; ++r)
        Pb[(wid*32 + ct*16 + q*4 + r)*F + ht*16 + cb] = acc[ct][ht][r];
}

template<int F>
__global__ void k_reduce(const float* __restrict__ P, float* __restrict__ OUT){
  int i = blockIdx.x*256 + threadIdx.x;    // < 512*F
  float s0=0.f, s1=0.f, s2=0.f, s3=0.f;
  for (int b = 0; b < NSPLIT; b += 4){
    s0 += P[(size_t)(b+0)*(512*F) + i];
    s1 += P[(size_t)(b+1)*(512*F) + i];
    s2 += P[(size_t)(b+2)*(512*F) + i];
    s3 += P[(size_t)(b+3)*(512*F) + i];
  }
  OUT[i] = (s0+s1)+(s2+s3);
}

// ---- struct_emb = w*SE ; Q = w * (struct_emb @ gcn_W) ----
__global__ void k_sepq(const float* __restrict__ SE, const float* __restrict__ w,
                       const float* __restrict__ gcn, float* __restrict__ sem,
                       float* __restrict__ Q){
  __shared__ float row[HH];
  int c = blockIdx.x, f = threadIdx.x; // 64 threads
  float wc = w[c];
  for (int h = f; h < HH; h += 64){
    float v = wc * SE[c*HH + h];
    row[h] = v;
    sem[c*HH + h] = v;
  }
  __syncthreads();
  float p = 0.f;
  for (int h = 0; h < HH; ++h) p += row[h] * gcn[h*FF + f];
  Q[c*FF + f] = wc * p;
}

// ---------------- MFMA GEMM: OUT[N, FT*16] (=|+=) A_bf16[N,K] @ B[K,F] ----------------
template<int FT, int K, int FSRC, int KSRCM, bool ACCUM, bool BIAS, bool OUTBF>
__global__ __launch_bounds__(1024) void k_mgemm(const unsigned short* __restrict__ A,
                                                const float* __restrict__ Bsrc,
                                                const float* __restrict__ bias,
                                                void* __restrict__ OUTv, int ost){
  __shared__ unsigned short Bt[FT*16*K];
  const int t = threadIdx.x;
  for (int i = t; i < FT*16*K; i += 1024){
    int f = i / K, k = i - f*K;
    float v = (f < FSRC) ? Bsrc[(size_t)(k & KSRCM)*FSRC + f] : 0.f;
    Bt[f*K + ((((k >> 3) ^ (f & 7)) << 3) | (k & 7))] = f2bf(v);
  }
  __syncthreads();
  const int lane = t & 63;
  const int wid  = t >> 6;           // 0..15
  const int cb   = lane & 15;
  const int q    = lane >> 4;
  const int s    = cb & 7;
  const int arow = min(blockIdx.x*256 + wid*16 + cb, NN-1);
  const unsigned short* ap = A + (size_t)arow*K + q*8;

  f32x4 acc[FT];
  #pragma unroll
  for (int ft = 0; ft < FT; ++ft) acc[ft] = (f32x4){0.f,0.f,0.f,0.f};

  #pragma unroll 2
  for (int kt = 0; kt < K/32; ++kt){
    s16x8 a = *(const s16x8*)(ap + kt*32);
    int boff = (((kt*4 + q) ^ s) << 3);
    #pragma unroll
    for (int ft = 0; ft < FT; ++ft){
      s16x8 b = *(const s16x8*)&Bt[(ft*16 + cb)*K + boff];
      acc[ft] = __builtin_amdgcn_mfma_f32_16x16x32_bf16(a, b, acc[ft], 0, 0, 0);
    }
  }

  const int nb = blockIdx.x*256 + wid*16 + q*4;
  #pragma unroll
  for (int ft = 0; ft < FT; ++ft){
    int f = ft*16 + cb;
    float bv = 0.f;
    if (BIAS) bv = (f < FSRC) ? bias[f] : 0.f;
    #pragma unroll
    for (int r = 0; r < 4; ++r){
      int n = nb + r;
      if (n < NN){
        size_t o = (size_t)n*ost + f;
        if (OUTBF){
          ((unsigned short*)OUTv)[o] = f2bf(acc[ft][r] + bv);
        } else {
          float* OUT = (float*)OUTv;
          if (ACCUM) OUT[o] += acc[ft][r];
          else       OUT[o] = acc[ft][r] + bv;
        }
      }
    }
  }
}

// ------- T[s,:] = sum over edges (src=s) of R[dst,:] (bf16 in/out, 4-deep MLP) -------
__global__ void k_esum(const int* __restrict__ rowstart, const int* __restrict__ sdst,
                       const unsigned short* __restrict__ R, unsigned short* __restrict__ T){
  int wg = (blockIdx.x*256 + threadIdx.x) >> 6;
  int lane = threadIdx.x & 63;
  if (wg >= NN) return;
  int e0 = rowstart[wg], e1 = rowstart[wg+1];
  float acc = 0.f;
  int e = e0;
  for (; e + 3 < e1; e += 4){
    int d0 = sdst[e], d1 = sdst[e+1], d2 = sdst[e+2], d3 = sdst[e+3];
    unsigned short r0 = R[(size_t)d0*FF + lane];
    unsigned short r1 = R[(size_t)d1*FF + lane];
    unsigned short r2 = R[(size_t)d2*FF + lane];
    unsigned short r3 = R[(size_t)d3*FF + lane];
    acc += bf2f(r0) + bf2f(r1) + bf2f(r2) + bf2f(r3);
  }
  for (; e < e1; ++e){
    int d = sdst[e];
    acc += bf2f(R[(size_t)d*FF + lane]);
  }
  T[(size_t)wg*FF + lane] = f2bf(acc);
}

// ---------------- softmax over C (axis 0) of w*U ----------------
__global__ void k_softmax(const float* __restrict__ U, const float* __restrict__ w,
                          float* __restrict__ fa){
  __shared__ float red[CC];
  int f = blockIdx.x, t = threadIdx.x; // 512 threads
  float v = w[t] * U[t*FF + f];
  red[t] = v; __syncthreads();
  for (int sft = 256; sft > 0; sft >>= 1){
    if (t < sft) red[t] = fmaxf(red[t], red[t+sft]);
    __syncthreads();
  }
  float mx = red[0]; __syncthreads();
  float e = expf(v - mx);
  red[t] = e; __syncthreads();
  for (int sft = 256; sft > 0; sft >>= 1){
    if (t < sft) red[t] += red[t+sft];
    __syncthreads();
  }
  float sum = red[0];
  fa[t*FF + f] = e / sum;
}

// ---------------- small GEMMs ----------------
__global__ void k_fe(const float* __restrict__ fa, const float* __restrict__ sem,
                     float* __restrict__ FE){
  int g = blockIdx.x, h = threadIdx.x; // 128
  float a = 0.f;
  for (int c = 0; c < CC; ++c) a += fa[c*FF + g] * sem[c*HH + h];
  FE[g*HH + h] = a;
}
__global__ void k_fw(const float* __restrict__ FE, const float* __restrict__ linW,
                     float* __restrict__ FW){
  int g = blockIdx.x, f = threadIdx.x; // 128, guard 100
  if (f >= 100) return;
  float a = 0.f;
  for (int h = 0; h < HH; ++h) a += FE[g*HH + h] * linW[(256 + h)*100 + f];
  FW[g*100 + f] = a;
}
__global__ void k_m(const float* __restrict__ sem, const float* __restrict__ fa,
                    const float* __restrict__ FW, const float* __restrict__ linW,
                    const float* __restrict__ w, float* __restrict__ M){
  int c = blockIdx.x, f = threadIdx.x; // 128, guard 100
  if (f >= 100) return;
  float a = 0.f;
  for (int h = 0; h < HH; ++h) a += sem[c*HH + h] * linW[(128 + h)*100 + f];
  for (int g = 0; g < FF; ++g) a += fa[c*FF + g] * FW[g*100 + f];
  M[c*100 + f] = w[c] * a;
}

// ---------------- edge scoring: pred[e] = X[a].X[b] (stride XST, pad cols = 0) ----------------
__global__ __launch_bounds__(256) void k_edot(const int* __restrict__ sedge,
                                              const float* __restrict__ X,
                                              float* __restrict__ out){
  int hw = (blockIdx.x*256 + threadIdx.x) >> 5;
  int hl = threadIdx.x & 31;
  if (hw >= ESN) return;
  int a = sedge[hw];
  int b = sedge[ESN + hw];
  float p = 0.f;
  if (hl < 28){
    float4 xa = *(const float4*)(X + (size_t)a*XST + hl*4);
    float4 xb = *(const float4*)(X + (size_t)b*XST + hl*4);
    p = xa.x*xb.x + xa.y*xb.y + xa.z*xb.z + xa.w*xb.w;
  }
  #pragma unroll
  for (int off = 16; off > 0; off >>= 1)
    p += __shfl_down(p, off, 32);
  if (hl == 0) out[hw] = p;
}

extern "C" void kernel_launch(void* const* d_in, const int* in_sizes, int n_in,
                              void* d_out, int out_size, void* d_ws, size_t ws_size,
                              hipStream_t stream){
  (void)in_sizes; (void)n_in; (void)out_size; (void)ws_size;
  const int*   lanef = (const int*)  d_in[0];
  const int*   typef = (const int*)  d_in[1];
  const int*   lenf  = (const int*)  d_in[2];
  const int*   nodef = (const int*)  d_in[3];
  const int*   adj   = (const int*)  d_in[4];
  const float* S     = (const float*)d_in[6];
  const int*   sedge = (const int*)  d_in[7];
  const float* WL    = (const float*)d_in[8];
  const float* WT    = (const float*)d_in[9];
  const float* WLen  = (const float*)d_in[10];
  const float* WNode = (const float*)d_in[11];
  const float* gcn   = (const float*)d_in[12];
  const float* linW  = (const float*)d_in[13];
  const float* linB  = (const float*)d_in[14];
  float* out = (float*)d_out;

  char* p = (char*)d_ws;
  auto alloc = [&](size_t bytes) -> void* {
    void* r = (void*)p;
    p += (bytes + 255) & ~(size_t)255;
    return r;
  };
  float* csb = (float*)alloc((size_t)PREP_B*512*4);   // 1.28 MB per-block colsum partials
  float* w   = (float*)alloc(CC*4);
  float* SE  = (float*)alloc(CC*HH*4);
  float* sem = (float*)alloc(CC*HH*4);
  float* Q   = (float*)alloc(CC*FF*4);
  float* U   = (float*)alloc(CC*FF*4);
  float* fa  = (float*)alloc(CC*FF*4);
  float* FE  = (float*)alloc(FF*HH*4);
  float* FW  = (float*)alloc(FF*100*4);
  float* M   = (float*)alloc(CC*100*4);
  int* cnt      = (int*)alloc((size_t)NN*4);
  int* rowstart = (int*)alloc((size_t)(NN+1)*4);
  int* cursor   = (int*)alloc((size_t)NN*4);
  int* bsum     = (int*)alloc(512*4);
  int* boff     = (int*)alloc(512*4);
  int* sdst     = (int*)alloc((size_t)EE*4);
  unsigned short* S_bf = (unsigned short*)alloc((size_t)NN*CC*2);   // 102.4 MB
  unsigned short* rf2  = (unsigned short*)alloc((size_t)NN*256*2);  // 51.2 MB
  // Region A (52.4 MB), time-multiplexed:
  //   phase 1: Ppart128 = NSPLIT*512*128*4 = 52.4 MB   (dead after k_reduce<128>)
  //   phase 2: R_bf @+0 (12.8) | T_bf @+12.8 (12.8) | Ppart64 @+25.6 (26.2)
  //   phase 3: X fp32 [NN,112] = 44.8 MB @+0           (R/T/Ppart64 dead by then)
  char* A = (char*)alloc((size_t)NSPLIT*512*128*4);
  float* Ppart128 = (float*)A;
  unsigned short* R_bf = (unsigned short*)A;
  unsigned short* T_bf = (unsigned short*)(A + (size_t)NN*FF*2);
  float* Ppart64 = (float*)(A + (size_t)2*NN*FF*2);
  float* X = (float*)A;

  const int NB = (NN + 255) / 256;   // 391

  k_init<<<NB, 256, 0, stream>>>(cnt);
  k_prep<<<PREP_B, 256, 0, stream>>>(S, csb, S_bf);
  k_w<<<1, 512, 0, stream>>>(csb, w);
  k_rf<<<(NN*32)/256, 256, 0, stream>>>(lanef, typef, lenf, nodef, WL, WT, WLen, WNode, rf2);

  k_hist<<<(EE+255)/256, 256, 0, stream>>>(adj, cnt);
  k_scan_a<<<NB, 256, 0, stream>>>(cnt, rowstart, bsum);
  k_scan_b<<<1, 512, 0, stream>>>(bsum, boff, NB);
  k_scan_c<<<NB, 256, 0, stream>>>(rowstart, boff, cursor);
  k_scatter<<<(EE+255)/256, 256, 0, stream>>>(adj, cursor, sdst);

  // SE = S^T @ rf_hi (MFMA split-k + reduce)
  k_tgemm<128,256><<<NSPLIT, 1024, 0, stream>>>(S_bf, rf2, Ppart128);
  k_reduce<128><<<(512*128)/256, 256, 0, stream>>>(Ppart128, SE);
  k_sepq<<<CC, 64, 0, stream>>>(SE, w, gcn, sem, Q);
  // R = S @ Q (bf16 out)
  k_mgemm<4,512,64,511,false,false,true><<<NB, 1024, 0, stream>>>(S_bf, Q, nullptr, R_bf, FF);
  k_esum<<<(NN*64)/256, 256, 0, stream>>>(rowstart, sdst, R_bf, T_bf);
  // U = S^T @ T
  k_tgemm<64,64><<<NSPLIT, 1024, 0, stream>>>(S_bf, T_bf, Ppart64);
  k_reduce<64><<<(512*64)/256, 256, 0, stream>>>(Ppart64, U);
  k_softmax<<<FF, 512, 0, stream>>>(U, w, fa);
  k_fe<<<FF, 128, 0, stream>>>(fa, sem, FE);
  k_fw<<<FF, 128, 0, stream>>>(FE, linW, FW);
  k_m<<<CC, 128, 0, stream>>>(sem, fa, FW, linW, w, M);

  // X = S@M + bias  (K=512), then X += [rf_hi|rf_lo]@W1 (K=256, rows k&127)
  k_mgemm<7,512,100,511,false,true ,false><<<NB, 1024, 0, stream>>>(S_bf, M, linB, X, XST);
  k_mgemm<7,256,100,127,true ,false,false><<<NB, 1024, 0, stream>>>(rf2, linW, nullptr, X, XST);

  k_edot<<<(ESN*32)/256, 256, 0, stream>>>(sedge, X, out);
}